// Round 3
// baseline (2117.638 us; speedup 1.0000x reference)
//
#include <hip/hip_runtime.h>
#include <math.h>

#define B_ 2
#define N_ 1024
#define DIM_ 256
#define DEPTH_ 4
#define HEADS_ 4
#define DHEAD_ 64
#define INNER_ 256
#define SCALE_ 0.125f
#define STEP_ 0.1f
#define LAMBD_ 0.1f
#define EPS_ 1e-5f

// ---------------- reductions (256-thread blocks = 4 waves of 64) ----------------
__device__ __forceinline__ float2 blockReduceSum2(float a, float b) {
    __shared__ float smA[4], smB[4];
    for (int o = 32; o > 0; o >>= 1) {
        a += __shfl_down(a, o, 64);
        b += __shfl_down(b, o, 64);
    }
    int wave = threadIdx.x >> 6, lane = threadIdx.x & 63;
    __syncthreads();
    if (lane == 0) { smA[wave] = a; smB[wave] = b; }
    __syncthreads();
    float ra = smA[0] + smA[1] + smA[2] + smA[3];
    float rb = smB[0] + smB[1] + smB[2] + smB[3];
    return make_float2(ra, rb);
}

// ---------------- complex layernorm: one block per row of DIM elements ----------------
__global__ void ln_kernel(const float* __restrict__ xr, const float* __restrict__ xi,
                          const float* __restrict__ wr, const float* __restrict__ wi,
                          const float* __restrict__ br, const float* __restrict__ bi,
                          float* __restrict__ outr, float* __restrict__ outi) {
    int row = blockIdx.x;
    int t = threadIdx.x;
    int idx = row * DIM_ + t;
    float xre = xr[idx], xim = xi[idx];
    float2 s = blockReduceSum2(xre, xim);
    float mre = s.x * (1.f / DIM_), mim = s.y * (1.f / DIM_);
    float dr = xre - mre, di = xim - mim;
    float2 v = blockReduceSum2(dr * dr, di * di);
    float c = v.x * (1.f / DIM_) + EPS_;   // var.real + EPS
    float d = v.y * (1.f / DIM_);          // var.imag (>= 0)
    float r = sqrtf(c * c + d * d);
    float sre = sqrtf(0.5f * (r + c));
    float sim = sqrtf(fmaxf(0.5f * (r - c), 0.f));
    float inv = 1.f / r;                   // |sqrt(z)|^2 = |z| = r
    float nr = (dr * sre + di * sim) * inv;
    float ni = (di * sre - dr * sim) * inv;
    float wre = wr[t], wim = wi[t];
    outr[idx] = wre * nr - wim * ni + br[t];
    outi[idx] = wre * ni + wim * nr + bi[t];
}

// ---------------- generic tiled complex GEMM (A [M,K] x B^T, B [Nn,K]) ----------------
template <bool TRANSB, bool CONJB>
__global__ __launch_bounds__(256)
void cgemm(const float* __restrict__ Ar, const float* __restrict__ Ai,
           const float* __restrict__ Br, const float* __restrict__ Bi,
           float* __restrict__ Cr, float* __restrict__ Ci,
           int M, int Nn, int K, int lda, int ldb, int ldc, float alpha) {
    __shared__ float Asr[64][17], Asi[64][17];
    __shared__ float Bsr[64][17], Bsi[64][17];

    int tileM = blockIdx.y * 64, tileN = blockIdx.x * 64;
    int tid = threadIdx.x;
    int tx = tid & 15, ty = tid >> 4;

    float accr[4][4] = {{0}}, acci[4][4] = {{0}};

    for (int k0 = 0; k0 < K; k0 += 16) {
#pragma unroll
        for (int i = 0; i < 4; i++) {           // A tile: 64x16
            int idx = tid + i * 256;
            int rr = idx >> 4, cc = idx & 15;
            int g = (tileM + rr) * lda + k0 + cc;
            Asr[rr][cc] = Ar[g];
            Asi[rr][cc] = Ai[g];
        }
#pragma unroll
        for (int i = 0; i < 4; i++) {           // B tile: 64(n) x 16(k)
            int idx = tid + i * 256;
            if (TRANSB) {
                int rr = idx >> 4, cc = idx & 15;
                int g = (tileN + rr) * ldb + k0 + cc;
                float vr = Br[g], vi = Bi[g];
                Bsr[rr][cc] = vr;
                Bsi[rr][cc] = CONJB ? -vi : vi;
            } else {
                int nn = idx & 63, kk = idx >> 6;
                int g = (k0 + kk) * ldb + tileN + nn;
                Bsr[nn][kk] = Br[g];
                Bsi[nn][kk] = Bi[g];
            }
        }
        __syncthreads();
#pragma unroll
        for (int k = 0; k < 16; k++) {
            float arv[4], aiv[4], brv[4], biv[4];
#pragma unroll
            for (int i = 0; i < 4; i++) { arv[i] = Asr[ty * 4 + i][k]; aiv[i] = Asi[ty * 4 + i][k]; }
#pragma unroll
            for (int j = 0; j < 4; j++) { brv[j] = Bsr[tx * 4 + j][k]; biv[j] = Bsi[tx * 4 + j][k]; }
#pragma unroll
            for (int i = 0; i < 4; i++)
#pragma unroll
                for (int j = 0; j < 4; j++) {
                    accr[i][j] += arv[i] * brv[j] - aiv[i] * biv[j];
                    acci[i][j] += arv[i] * biv[j] + aiv[i] * brv[j];
                }
        }
        __syncthreads();
    }
#pragma unroll
    for (int i = 0; i < 4; i++) {
        int m = tileM + ty * 4 + i;
#pragma unroll
        for (int j = 0; j < 4; j++) {
            int n = tileN + tx * 4 + j;
            int g = m * ldc + n;
            Cr[g] = alpha * accr[i][j];
            Ci[g] = alpha * acci[i][j];
        }
    }
}

// ---------------- fused attention (flash-style, online softmax on |s|) ----------------
__global__ __launch_bounds__(256)
void attn_fused(const float* __restrict__ wr, const float* __restrict__ wi,
                float* __restrict__ outr, float* __restrict__ outi) {
    __shared__ float Qr[32][65], Qi[32][65];
    __shared__ float Kr[64][65], Ki[64][65];

    int z = blockIdx.y;
    int bb = z >> 2, hh = z & 3;
    const size_t base = (size_t)bb * N_ * INNER_ + (size_t)hh * DHEAD_;
    int row0 = blockIdx.x * 32;
    int tid = threadIdx.x;
    int tx = tid & 15, ty = tid >> 4;        // thread owns rows {2ty, 2ty+1}, cols tx*4..tx*4+3
    int lanebase = tid & 48;                 // wave-local base of this row-group's 16 lanes

#pragma unroll
    for (int q = 0; q < 8; q++) {
        int idx = q * 256 + tid;
        int r = idx >> 6, c = idx & 63;
        size_t g = base + (size_t)(row0 + r) * INNER_ + c;
        Qr[r][c] = wr[g];
        Qi[r][c] = wi[g];
    }

    float m[2] = {-1e30f, -1e30f}, l[2] = {0.f, 0.f};
    float Or[2][4] = {{0}}, Oi[2][4] = {{0}};

    for (int kt = 0; kt < N_ / 64; kt++) {
        __syncthreads();
#pragma unroll
        for (int q = 0; q < 16; q++) {
            int idx = q * 256 + tid;
            int r = idx >> 6, c = idx & 63;
            size_t g = base + (size_t)(kt * 64 + r) * INNER_ + c;
            Kr[r][c] = wr[g];
            Ki[r][c] = wi[g];
        }
        __syncthreads();

        // S = SCALE * Q K^H
        float Sr[2][4] = {{0}}, Si[2][4] = {{0}};
#pragma unroll 4
        for (int d = 0; d < 64; d++) {
            float qr0 = Qr[2 * ty][d],     qi0 = Qi[2 * ty][d];
            float qr1 = Qr[2 * ty + 1][d], qi1 = Qi[2 * ty + 1][d];
#pragma unroll
            for (int j = 0; j < 4; j++) {
                float kr = Kr[tx * 4 + j][d], ki = Ki[tx * 4 + j][d];
                Sr[0][j] += qr0 * kr + qi0 * ki;   // q * conj(k)
                Si[0][j] += qi0 * kr - qr0 * ki;
                Sr[1][j] += qr1 * kr + qi1 * ki;
                Si[1][j] += qi1 * kr - qr1 * ki;
            }
        }

        float mag[2][4];
        float mx[2] = {-1e30f, -1e30f};
#pragma unroll
        for (int rr = 0; rr < 2; rr++)
#pragma unroll
            for (int j = 0; j < 4; j++) {
                Sr[rr][j] *= SCALE_; Si[rr][j] *= SCALE_;
                mag[rr][j] = sqrtf(Sr[rr][j] * Sr[rr][j] + Si[rr][j] * Si[rr][j]);
                mx[rr] = fmaxf(mx[rr], mag[rr][j]);
            }
#pragma unroll
        for (int o = 1; o < 16; o <<= 1) {
            mx[0] = fmaxf(mx[0], __shfl_xor(mx[0], o, 64));
            mx[1] = fmaxf(mx[1], __shfl_xor(mx[1], o, 64));
        }

        float Pr0[4], Pi0[4], Pr1[4], Pi1[4];
        float ps[2] = {0.f, 0.f};
#pragma unroll
        for (int rr = 0; rr < 2; rr++) {
            float newm = fmaxf(m[rr], mx[rr]);
            float a = expf(m[rr] - newm);
            m[rr] = newm;
            l[rr] *= a;
#pragma unroll
            for (int j = 0; j < 4; j++) {
                float p = expf(mag[rr][j] - newm);
                ps[rr] += p;
                float sc = (mag[rr][j] > 0.f) ? (p / mag[rr][j]) : 0.f;
                float pr = (mag[rr][j] > 0.f) ? Sr[rr][j] * sc : p;
                float pi = Si[rr][j] * sc;
                if (rr == 0) { Pr0[j] = pr; Pi0[j] = pi; }
                else         { Pr1[j] = pr; Pi1[j] = pi; }
            }
#pragma unroll
            for (int j = 0; j < 4; j++) {
                Or[rr][j] *= a;
                Oi[rr][j] *= a;
            }
        }
#pragma unroll
        for (int o = 1; o < 16; o <<= 1) {
            ps[0] += __shfl_xor(ps[0], o, 64);
            ps[1] += __shfl_xor(ps[1], o, 64);
        }
        l[0] += ps[0];
        l[1] += ps[1];

        // O += P @ V (V = K tile, no conj)
        for (int g = 0; g < 16; g++) {
            int src = lanebase + g;
#pragma unroll
            for (int u = 0; u < 4; u++) {
                int j = g * 4 + u;
                float pr0 = __shfl(Pr0[u], src, 64);
                float pi0 = __shfl(Pi0[u], src, 64);
                float pr1 = __shfl(Pr1[u], src, 64);
                float pi1 = __shfl(Pi1[u], src, 64);
#pragma unroll
                for (int jj = 0; jj < 4; jj++) {
                    float vr = Kr[j][tx * 4 + jj], vi = Ki[j][tx * 4 + jj];
                    Or[0][jj] += pr0 * vr - pi0 * vi;
                    Oi[0][jj] += pr0 * vi + pi0 * vr;
                    Or[1][jj] += pr1 * vr - pi1 * vi;
                    Oi[1][jj] += pr1 * vi + pi1 * vr;
                }
            }
        }
    }

#pragma unroll
    for (int rr = 0; rr < 2; rr++) {
        float invl = 1.f / l[rr];
        int r = row0 + 2 * ty + rr;
        size_t g = base + (size_t)r * INNER_ + tx * 4;
#pragma unroll
        for (int jj = 0; jj < 4; jj++) {
            outr[g + jj] = Or[rr][jj] * invl;
            outi[g + jj] = Oi[rr][jj] * invl;
        }
    }
}

// ---------------- epilogues ----------------
__global__ void bias_res(const float* __restrict__ tr, const float* __restrict__ ti,
                         const float* __restrict__ br, const float* __restrict__ bi,
                         float* __restrict__ xr, float* __restrict__ xi) {
    int idx = blockIdx.x * 256 + threadIdx.x;
    int d = idx & (DIM_ - 1);
    xr[idx] = tr[idx] + br[d] + xr[idx];
    xi[idx] = ti[idx] + bi[d] + xi[idx];
}

__global__ void ff_ep(const float* __restrict__ xnr, const float* __restrict__ xni,
                      const float* __restrict__ x1r, const float* __restrict__ x1i,
                      float* __restrict__ xr, float* __restrict__ xi) {
    int idx = blockIdx.x * 256 + threadIdx.x;
    float zr = xnr[idx] + STEP_ * x1r[idx] - STEP_ * LAMBD_;
    float zi = xni[idx] + STEP_ * x1i[idx];
    xr[idx] = fmaxf(zr, 0.f);
    xi[idx] = fmaxf(zi, 0.f);
}

// planar pack: real plane at [0, S), imag plane at [S, 2S), bounds-guarded
__global__ void pack_planar(const float* __restrict__ xr, const float* __restrict__ xi,
                            float* __restrict__ out, int S, int cap) {
    int idx = blockIdx.x * 256 + threadIdx.x;
    if (idx < cap) out[idx] = xr[idx];
    if (S + idx < cap) out[S + idx] = xi[idx];
}

// real-only pack (fallback if out_size == S)
__global__ void pack_real(const float* __restrict__ xr, float* __restrict__ out, int cap) {
    int idx = blockIdx.x * 256 + threadIdx.x;
    if (idx < cap) out[idx] = xr[idx];
}

// ---------------- host orchestration ----------------
extern "C" void kernel_launch(void* const* d_in, const int* in_sizes, int n_in,
                              void* d_out, int out_size, void* d_ws, size_t ws_size,
                              hipStream_t stream) {
    const float* in_xre = (const float*)d_in[0];
    const float* in_xim = (const float*)d_in[1];
    const float* ln1wr = (const float*)d_in[2];
    const float* ln1wi = (const float*)d_in[3];
    const float* ln1br = (const float*)d_in[4];
    const float* ln1bi = (const float*)d_in[5];
    const float* qkvr  = (const float*)d_in[6];
    const float* qkvi  = (const float*)d_in[7];
    const float* outwr = (const float*)d_in[8];
    const float* outwi = (const float*)d_in[9];
    const float* outbr = (const float*)d_in[10];
    const float* outbi = (const float*)d_in[11];
    const float* ln2wr = (const float*)d_in[12];
    const float* ln2wi = (const float*)d_in[13];
    const float* ln2br = (const float*)d_in[14];
    const float* ln2bi = (const float*)d_in[15];
    const float* ffr   = (const float*)d_in[16];
    const float* ffi   = (const float*)d_in[17];

    const size_t S = (size_t)B_ * N_ * DIM_;          // 524288

    float* ws  = (float*)d_ws;
    float* xre = ws;            float* xim = xre + S;
    float* xnr = xim + S;       float* xni = xnr + S;
    float* wre = xni + S;       float* wim = wre + S;
    float* tre = wim + S;       float* tim = tre + S;
    float* aor = tim + S;       float* aoi = aor + S;   // total 10*S floats = 20 MB

    hipMemcpyAsync(xre, in_xre, S * sizeof(float), hipMemcpyDeviceToDevice, stream);
    hipMemcpyAsync(xim, in_xim, S * sizeof(float), hipMemcpyDeviceToDevice, stream);

    const int MR = B_ * N_;              // 2048 rows
    dim3 gProj(INNER_ / 64, MR / 64);    // 4 x 32
    dim3 gAttn(N_ / 32, B_ * HEADS_);    // 32 x 8 = 256 blocks
    int eBlocks = (int)(S / 256);

    for (int l = 0; l < DEPTH_; l++) {
        ln_kernel<<<MR, DIM_, 0, stream>>>(xre, xim,
            ln1wr + l * DIM_, ln1wi + l * DIM_, ln1br + l * DIM_, ln1bi + l * DIM_, xnr, xni);

        cgemm<true, false><<<gProj, 256, 0, stream>>>(xnr, xni,
            qkvr + (size_t)l * INNER_ * DIM_, qkvi + (size_t)l * INNER_ * DIM_,
            wre, wim, MR, INNER_, DIM_, DIM_, DIM_, INNER_, 1.f);

        attn_fused<<<gAttn, 256, 0, stream>>>(wre, wim, aor, aoi);

        cgemm<true, false><<<gProj, 256, 0, stream>>>(aor, aoi,
            outwr + (size_t)l * DIM_ * INNER_, outwi + (size_t)l * DIM_ * INNER_,
            tre, tim, MR, DIM_, INNER_, INNER_, INNER_, DIM_, 1.f);

        bias_res<<<eBlocks, 256, 0, stream>>>(tre, tim, outbr + l * DIM_, outbi + l * DIM_, xre, xim);

        ln_kernel<<<MR, DIM_, 0, stream>>>(xre, xim,
            ln2wr + l * DIM_, ln2wi + l * DIM_, ln2br + l * DIM_, ln2bi + l * DIM_, xnr, xni);

        cgemm<true, false><<<gProj, 256, 0, stream>>>(xnr, xni,
            ffr + (size_t)l * DIM_ * DIM_, ffi + (size_t)l * DIM_ * DIM_,
            tre, tim, MR, DIM_, DIM_, DIM_, DIM_, DIM_, 1.f);

        ff_ep<<<eBlocks, 256, 0, stream>>>(xnr, xni, tre, tim, xre, xim);
    }

    if (out_size >= (int)(2 * S)) {
        // planar: [real plane | imag plane]
        pack_planar<<<eBlocks, 256, 0, stream>>>(xre, xim, (float*)d_out, (int)S, out_size);
    } else {
        pack_real<<<eBlocks, 256, 0, stream>>>(xre, (float*)d_out, out_size);
    }
}

// Round 4
// 1470.345 us; speedup vs baseline: 1.4402x; 1.4402x over previous
//
#include <hip/hip_runtime.h>
#include <math.h>

#define B_ 2
#define N_ 1024
#define DIM_ 256
#define DEPTH_ 4
#define HEADS_ 4
#define DHEAD_ 64
#define INNER_ 256
#define SCALE_ 0.125f
#define STEP_ 0.1f
#define LAMBD_ 0.1f
#define EPS_ 1e-5f

typedef __attribute__((ext_vector_type(8))) short short8;
typedef __attribute__((ext_vector_type(4))) float f32x4;

// ---------------- bf16 split helpers ----------------
__device__ __forceinline__ unsigned short bf16_rne(float x) {
    unsigned u = __float_as_uint(x);
    unsigned r = (u + 0x7FFFu + ((u >> 16) & 1u)) >> 16;
    return (unsigned short)r;
}
__device__ __forceinline__ float bf16_tof(unsigned short h) {
    return __uint_as_float(((unsigned)h) << 16);
}
__device__ __forceinline__ void split2(float x, unsigned short& hi, unsigned short& lo) {
    hi = bf16_rne(x);
    lo = bf16_rne(x - bf16_tof(hi));
}

__device__ __forceinline__ f32x4 mfma16(short8 a, short8 b, f32x4 c) {
    return __builtin_amdgcn_mfma_f32_16x16x32_bf16(a, b, c, 0, 0, 0);
}

// ---------------- reductions (256-thread blocks = 4 waves of 64) ----------------
__device__ __forceinline__ float2 blockReduceSum2(float a, float b) {
    __shared__ float smA[4], smB[4];
    for (int o = 32; o > 0; o >>= 1) {
        a += __shfl_down(a, o, 64);
        b += __shfl_down(b, o, 64);
    }
    int wave = threadIdx.x >> 6, lane = threadIdx.x & 63;
    __syncthreads();
    if (lane == 0) { smA[wave] = a; smB[wave] = b; }
    __syncthreads();
    float ra = smA[0] + smA[1] + smA[2] + smA[3];
    float rb = smB[0] + smB[1] + smB[2] + smB[3];
    return make_float2(ra, rb);
}

// ---------------- complex layernorm + fused bf16-split of output ----------------
__global__ void ln_kernel(const float* __restrict__ xr, const float* __restrict__ xi,
                          const float* __restrict__ wr, const float* __restrict__ wi,
                          const float* __restrict__ br, const float* __restrict__ bi,
                          float* __restrict__ outr, float* __restrict__ outi,
                          unsigned short* __restrict__ planes, int S) {
    int row = blockIdx.x;
    int t = threadIdx.x;
    int idx = row * DIM_ + t;
    float xre = xr[idx], xim = xi[idx];
    float2 s = blockReduceSum2(xre, xim);
    float mre = s.x * (1.f / DIM_), mim = s.y * (1.f / DIM_);
    float dr = xre - mre, di = xim - mim;
    float2 v = blockReduceSum2(dr * dr, di * di);
    float c = v.x * (1.f / DIM_) + EPS_;
    float d = v.y * (1.f / DIM_);
    float r = sqrtf(c * c + d * d);
    float sre = sqrtf(0.5f * (r + c));
    float sim = sqrtf(fmaxf(0.5f * (r - c), 0.f));
    float inv = 1.f / r;
    float nr = (dr * sre + di * sim) * inv;
    float ni = (di * sre - dr * sim) * inv;
    float wre = wr[t], wim = wi[t];
    float orr = wre * nr - wim * ni + br[t];
    float oii = wre * ni + wim * nr + bi[t];
    outr[idx] = orr;
    outi[idx] = oii;
    unsigned short rh, rl, ih, il;
    split2(orr, rh, rl);
    split2(oii, ih, il);
    planes[0 * S + idx] = rh;
    planes[1 * S + idx] = rl;
    planes[2 * S + idx] = ih;
    planes[3 * S + idx] = il;
}

// ---------------- split fp32 pair -> 4 bf16 planes ----------------
__global__ void split4(const float* __restrict__ ar, const float* __restrict__ ai,
                       unsigned short* __restrict__ planes, int S) {
    int idx = blockIdx.x * 256 + threadIdx.x;
    unsigned short rh, rl, ih, il;
    split2(ar[idx], rh, rl);
    split2(ai[idx], ih, il);
    planes[0 * S + idx] = rh;
    planes[1 * S + idx] = rl;
    planes[2 * S + idx] = ih;
    planes[3 * S + idx] = il;
}

// ---------------- weight split: [DEPTH][256x256] cplx -> per-layer 4 planes ----------------
__global__ void wsplit(const float* __restrict__ wr, const float* __restrict__ wi,
                       unsigned short* __restrict__ planes) {
    int idx = blockIdx.x * 256 + threadIdx.x;   // DEPTH*65536 total
    int l = idx >> 16, e = idx & 65535;
    unsigned short rh, rl, ih, il;
    split2(wr[idx], rh, rl);
    split2(wi[idx], ih, il);
    size_t base = (size_t)l * 4 * 65536;
    planes[base + 0 * 65536 + e] = rh;
    planes[base + 1 * 65536 + e] = rl;
    planes[base + 2 * 65536 + e] = ih;
    planes[base + 3 * 65536 + e] = il;
}

// ---------------- MFMA complex GEMM: C[M,256] = A[M,256] x B^T (B[256,256]) ----------------
// A, B given as 4 bf16 planes each (rh, rl, ih, il), plane strides aStride / 65536.
// Per real product: hh + hl + lh MFMA passes. Cr = P_rr - P_ii ; Ci = P_ri + P_ir.
// grid: (N/32=8, M/32), block: 64 (one wave). Fragments load direct from global (L2).
__global__ __launch_bounds__(64)
void gemm_mfma(const unsigned short* __restrict__ Ap, int aStride,
               const unsigned short* __restrict__ Bp,
               float* __restrict__ Cr, float* __restrict__ Ci) {
    const int K = 256;
    int tileN = blockIdx.x * 32, tileM = blockIdx.y * 32;
    int lane = threadIdx.x;
    int m16 = lane & 15, quad = lane >> 4;

    f32x4 accP[2][2], accN[2][2], accI[2][2];
#pragma unroll
    for (int mi = 0; mi < 2; mi++)
#pragma unroll
        for (int ni = 0; ni < 2; ni++) {
            accP[mi][ni] = (f32x4){0.f, 0.f, 0.f, 0.f};
            accN[mi][ni] = (f32x4){0.f, 0.f, 0.f, 0.f};
            accI[mi][ni] = (f32x4){0.f, 0.f, 0.f, 0.f};
        }

#pragma unroll
    for (int k0 = 0; k0 < 256; k0 += 32) {
        int kb = k0 + quad * 8;
        short8 a[4][2], b[4][2];    // [plane][m-/n-subtile]
#pragma unroll
        for (int p = 0; p < 4; p++) {
#pragma unroll
            for (int s = 0; s < 2; s++) {
                a[p][s] = *(const short8*)(Ap + (size_t)p * aStride + (size_t)(tileM + s * 16 + m16) * K + kb);
                b[p][s] = *(const short8*)(Bp + (size_t)p * 65536  + (size_t)(tileN + s * 16 + m16) * K + kb);
            }
        }
        // planes: 0=rh 1=rl 2=ih 3=il
#pragma unroll
        for (int mi = 0; mi < 2; mi++)
#pragma unroll
            for (int ni = 0; ni < 2; ni++) {
                f32x4 p1 = accP[mi][ni], p2 = accN[mi][ni], p3 = accI[mi][ni];
                p1 = mfma16(a[0][mi], b[0][ni], p1);   // Ar*Br
                p1 = mfma16(a[0][mi], b[1][ni], p1);
                p1 = mfma16(a[1][mi], b[0][ni], p1);
                p2 = mfma16(a[2][mi], b[2][ni], p2);   // Ai*Bi
                p2 = mfma16(a[2][mi], b[3][ni], p2);
                p2 = mfma16(a[3][mi], b[2][ni], p2);
                p3 = mfma16(a[0][mi], b[2][ni], p3);   // Ar*Bi
                p3 = mfma16(a[0][mi], b[3][ni], p3);
                p3 = mfma16(a[1][mi], b[2][ni], p3);
                p3 = mfma16(a[2][mi], b[0][ni], p3);   // Ai*Br
                p3 = mfma16(a[2][mi], b[1][ni], p3);
                p3 = mfma16(a[3][mi], b[0][ni], p3);
                accP[mi][ni] = p1; accN[mi][ni] = p2; accI[mi][ni] = p3;
            }
    }

    // C/D layout: col = lane&15, row = quad*4 + reg  [m89]
#pragma unroll
    for (int mi = 0; mi < 2; mi++)
#pragma unroll
        for (int ni = 0; ni < 2; ni++)
#pragma unroll
            for (int r = 0; r < 4; r++) {
                int row = tileM + mi * 16 + quad * 4 + r;
                int col = tileN + ni * 16 + m16;
                Cr[row * 256 + col] = accP[mi][ni][r] - accN[mi][ni][r];
                Ci[row * 256 + col] = accI[mi][ni][r];
            }
}

// ---------------- fused attention (flash-style, online softmax on |s|) — UNCHANGED ----------------
__global__ __launch_bounds__(256)
void attn_fused(const float* __restrict__ wr, const float* __restrict__ wi,
                float* __restrict__ outr, float* __restrict__ outi) {
    __shared__ float Qr[32][65], Qi[32][65];
    __shared__ float Kr[64][65], Ki[64][65];

    int z = blockIdx.y;
    int bb = z >> 2, hh = z & 3;
    const size_t base = (size_t)bb * N_ * INNER_ + (size_t)hh * DHEAD_;
    int row0 = blockIdx.x * 32;
    int tid = threadIdx.x;
    int tx = tid & 15, ty = tid >> 4;
    int lanebase = tid & 48;

#pragma unroll
    for (int q = 0; q < 8; q++) {
        int idx = q * 256 + tid;
        int r = idx >> 6, c = idx & 63;
        size_t g = base + (size_t)(row0 + r) * INNER_ + c;
        Qr[r][c] = wr[g];
        Qi[r][c] = wi[g];
    }

    float m[2] = {-1e30f, -1e30f}, l[2] = {0.f, 0.f};
    float Or[2][4] = {{0}}, Oi[2][4] = {{0}};

    for (int kt = 0; kt < N_ / 64; kt++) {
        __syncthreads();
#pragma unroll
        for (int q = 0; q < 16; q++) {
            int idx = q * 256 + tid;
            int r = idx >> 6, c = idx & 63;
            size_t g = base + (size_t)(kt * 64 + r) * INNER_ + c;
            Kr[r][c] = wr[g];
            Ki[r][c] = wi[g];
        }
        __syncthreads();

        float Sr[2][4] = {{0}}, Si[2][4] = {{0}};
#pragma unroll 4
        for (int d = 0; d < 64; d++) {
            float qr0 = Qr[2 * ty][d],     qi0 = Qi[2 * ty][d];
            float qr1 = Qr[2 * ty + 1][d], qi1 = Qi[2 * ty + 1][d];
#pragma unroll
            for (int j = 0; j < 4; j++) {
                float kr = Kr[tx * 4 + j][d], ki = Ki[tx * 4 + j][d];
                Sr[0][j] += qr0 * kr + qi0 * ki;
                Si[0][j] += qi0 * kr - qr0 * ki;
                Sr[1][j] += qr1 * kr + qi1 * ki;
                Si[1][j] += qi1 * kr - qr1 * ki;
            }
        }

        float mag[2][4];
        float mx[2] = {-1e30f, -1e30f};
#pragma unroll
        for (int rr = 0; rr < 2; rr++)
#pragma unroll
            for (int j = 0; j < 4; j++) {
                Sr[rr][j] *= SCALE_; Si[rr][j] *= SCALE_;
                mag[rr][j] = sqrtf(Sr[rr][j] * Sr[rr][j] + Si[rr][j] * Si[rr][j]);
                mx[rr] = fmaxf(mx[rr], mag[rr][j]);
            }
#pragma unroll
        for (int o = 1; o < 16; o <<= 1) {
            mx[0] = fmaxf(mx[0], __shfl_xor(mx[0], o, 64));
            mx[1] = fmaxf(mx[1], __shfl_xor(mx[1], o, 64));
        }

        float Pr0[4], Pi0[4], Pr1[4], Pi1[4];
        float ps[2] = {0.f, 0.f};
#pragma unroll
        for (int rr = 0; rr < 2; rr++) {
            float newm = fmaxf(m[rr], mx[rr]);
            float a = expf(m[rr] - newm);
            m[rr] = newm;
            l[rr] *= a;
#pragma unroll
            for (int j = 0; j < 4; j++) {
                float p = expf(mag[rr][j] - newm);
                ps[rr] += p;
                float sc = (mag[rr][j] > 0.f) ? (p / mag[rr][j]) : 0.f;
                float pr = (mag[rr][j] > 0.f) ? Sr[rr][j] * sc : p;
                float pi = Si[rr][j] * sc;
                if (rr == 0) { Pr0[j] = pr; Pi0[j] = pi; }
                else         { Pr1[j] = pr; Pi1[j] = pi; }
            }
#pragma unroll
            for (int j = 0; j < 4; j++) {
                Or[rr][j] *= a;
                Oi[rr][j] *= a;
            }
        }
#pragma unroll
        for (int o = 1; o < 16; o <<= 1) {
            ps[0] += __shfl_xor(ps[0], o, 64);
            ps[1] += __shfl_xor(ps[1], o, 64);
        }
        l[0] += ps[0];
        l[1] += ps[1];

        for (int g = 0; g < 16; g++) {
            int src = lanebase + g;
#pragma unroll
            for (int u = 0; u < 4; u++) {
                int j = g * 4 + u;
                float pr0 = __shfl(Pr0[u], src, 64);
                float pi0 = __shfl(Pi0[u], src, 64);
                float pr1 = __shfl(Pr1[u], src, 64);
                float pi1 = __shfl(Pi1[u], src, 64);
#pragma unroll
                for (int jj = 0; jj < 4; jj++) {
                    float vr = Kr[j][tx * 4 + jj], vi = Ki[j][tx * 4 + jj];
                    Or[0][jj] += pr0 * vr - pi0 * vi;
                    Oi[0][jj] += pr0 * vi + pi0 * vr;
                    Or[1][jj] += pr1 * vr - pi1 * vi;
                    Oi[1][jj] += pr1 * vi + pi1 * vr;
                }
            }
        }
    }

#pragma unroll
    for (int rr = 0; rr < 2; rr++) {
        float invl = 1.f / l[rr];
        int r = row0 + 2 * ty + rr;
        size_t g = base + (size_t)r * INNER_ + tx * 4;
#pragma unroll
        for (int jj = 0; jj < 4; jj++) {
            outr[g + jj] = Or[rr][jj] * invl;
            outi[g + jj] = Oi[rr][jj] * invl;
        }
    }
}

// ---------------- epilogues ----------------
__global__ void bias_res(const float* __restrict__ tr, const float* __restrict__ ti,
                         const float* __restrict__ br, const float* __restrict__ bi,
                         float* __restrict__ xr, float* __restrict__ xi) {
    int idx = blockIdx.x * 256 + threadIdx.x;
    int d = idx & (DIM_ - 1);
    xr[idx] = tr[idx] + br[d] + xr[idx];
    xi[idx] = ti[idx] + bi[d] + xi[idx];
}

__global__ void ff_ep(const float* __restrict__ xnr, const float* __restrict__ xni,
                      const float* __restrict__ x1r, const float* __restrict__ x1i,
                      float* __restrict__ xr, float* __restrict__ xi) {
    int idx = blockIdx.x * 256 + threadIdx.x;
    float zr = xnr[idx] + STEP_ * x1r[idx] - STEP_ * LAMBD_;
    float zi = xni[idx] + STEP_ * x1i[idx];
    xr[idx] = fmaxf(zr, 0.f);
    xi[idx] = fmaxf(zi, 0.f);
}

__global__ void pack_planar(const float* __restrict__ xr, const float* __restrict__ xi,
                            float* __restrict__ out, int S, int cap) {
    int idx = blockIdx.x * 256 + threadIdx.x;
    if (idx < cap) out[idx] = xr[idx];
    if (S + idx < cap) out[S + idx] = xi[idx];
}

__global__ void pack_real(const float* __restrict__ xr, float* __restrict__ out, int cap) {
    int idx = blockIdx.x * 256 + threadIdx.x;
    if (idx < cap) out[idx] = xr[idx];
}

// ---------------- host orchestration ----------------
extern "C" void kernel_launch(void* const* d_in, const int* in_sizes, int n_in,
                              void* d_out, int out_size, void* d_ws, size_t ws_size,
                              hipStream_t stream) {
    const float* in_xre = (const float*)d_in[0];
    const float* in_xim = (const float*)d_in[1];
    const float* ln1wr = (const float*)d_in[2];
    const float* ln1wi = (const float*)d_in[3];
    const float* ln1br = (const float*)d_in[4];
    const float* ln1bi = (const float*)d_in[5];
    const float* qkvr  = (const float*)d_in[6];
    const float* qkvi  = (const float*)d_in[7];
    const float* outwr = (const float*)d_in[8];
    const float* outwi = (const float*)d_in[9];
    const float* outbr = (const float*)d_in[10];
    const float* outbi = (const float*)d_in[11];
    const float* ln2wr = (const float*)d_in[12];
    const float* ln2wi = (const float*)d_in[13];
    const float* ln2br = (const float*)d_in[14];
    const float* ln2bi = (const float*)d_in[15];
    const float* ffr   = (const float*)d_in[16];
    const float* ffi   = (const float*)d_in[17];

    const size_t S = (size_t)B_ * N_ * DIM_;          // 524288
    const int    Si = (int)S;

    float* ws  = (float*)d_ws;
    float* xre = ws;            float* xim = xre + S;
    float* xnr = xim + S;       float* xni = xnr + S;
    float* wre = xni + S;       float* wim = wre + S;
    float* tre = wim + S;       float* tim = tre + S;
    float* aor = tim + S;       float* aoi = aor + S;   // 10*S fp32 = 20 MB

    unsigned short* xnp   = (unsigned short*)(aoi + S);        // 4*S bf16 = 4 MB
    unsigned short* aop   = xnp + 4 * S;                       // 4*S bf16 = 4 MB
    unsigned short* qkvp  = aop + 4 * S;                       // DEPTH*4*65536 = 2 MB
    unsigned short* outwp = qkvp + (size_t)DEPTH_ * 4 * 65536; // 2 MB
    unsigned short* ffp   = outwp + (size_t)DEPTH_ * 4 * 65536;// 2 MB  (total ~34 MB)

    hipMemcpyAsync(xre, in_xre, S * sizeof(float), hipMemcpyDeviceToDevice, stream);
    hipMemcpyAsync(xim, in_xim, S * sizeof(float), hipMemcpyDeviceToDevice, stream);

    // per-call weight split (weights are inputs; re-derived every launch)
    wsplit<<<DEPTH_ * 65536 / 256, 256, 0, stream>>>(qkvr, qkvi, qkvp);
    wsplit<<<DEPTH_ * 65536 / 256, 256, 0, stream>>>(outwr, outwi, outwp);
    wsplit<<<DEPTH_ * 65536 / 256, 256, 0, stream>>>(ffr, ffi, ffp);

    const int MR = B_ * N_;              // 2048 rows
    dim3 gGemm(INNER_ / 32, MR / 32);    // 8 x 64 = 512 single-wave blocks
    dim3 gAttn(N_ / 32, B_ * HEADS_);    // 32 x 8 = 256 blocks
    int eBlocks = (int)(S / 256);

    for (int l = 0; l < DEPTH_; l++) {
        ln_kernel<<<MR, DIM_, 0, stream>>>(xre, xim,
            ln1wr + l * DIM_, ln1wi + l * DIM_, ln1br + l * DIM_, ln1bi + l * DIM_,
            xnr, xni, xnp, Si);

        gemm_mfma<<<gGemm, 64, 0, stream>>>(xnp, Si, qkvp + (size_t)l * 4 * 65536, wre, wim);

        attn_fused<<<gAttn, 256, 0, stream>>>(wre, wim, aor, aoi);

        split4<<<eBlocks, 256, 0, stream>>>(aor, aoi, aop, Si);

        gemm_mfma<<<gGemm, 64, 0, stream>>>(aop, Si, outwp + (size_t)l * 4 * 65536, tre, tim);

        bias_res<<<eBlocks, 256, 0, stream>>>(tre, tim, outbr + l * DIM_, outbi + l * DIM_, xre, xim);

        ln_kernel<<<MR, DIM_, 0, stream>>>(xre, xim,
            ln2wr + l * DIM_, ln2wi + l * DIM_, ln2br + l * DIM_, ln2bi + l * DIM_,
            xnr, xni, xnp, Si);

        gemm_mfma<<<gGemm, 64, 0, stream>>>(xnp, Si, ffp + (size_t)l * 4 * 65536, tre, tim);

        ff_ep<<<eBlocks, 256, 0, stream>>>(xnr, xni, tre, tim, xre, xim);
    }

    if (out_size >= (int)(2 * S)) {
        pack_planar<<<eBlocks, 256, 0, stream>>>(xre, xim, (float*)d_out, Si, out_size);
    } else {
        pack_real<<<eBlocks, 256, 0, stream>>>(xre, (float*)d_out, out_size);
    }
}

// Round 5
// 687.813 us; speedup vs baseline: 3.0788x; 2.1377x over previous
//
#include <hip/hip_runtime.h>
#include <math.h>

#define B_ 2
#define N_ 1024
#define DIM_ 256
#define DEPTH_ 4
#define HEADS_ 4
#define DHEAD_ 64
#define INNER_ 256
#define SCALE_ 0.125f
#define STEP_ 0.1f
#define LAMBD_ 0.1f
#define EPS_ 1e-5f

typedef __attribute__((ext_vector_type(8))) short short8;
typedef __attribute__((ext_vector_type(4))) float f32x4;

// ---------------- bf16 split helpers ----------------
__device__ __forceinline__ unsigned short bf16_rne(float x) {
    unsigned u = __float_as_uint(x);
    unsigned r = (u + 0x7FFFu + ((u >> 16) & 1u)) >> 16;
    return (unsigned short)r;
}
__device__ __forceinline__ float bf16_tof(unsigned short h) {
    return __uint_as_float(((unsigned)h) << 16);
}
__device__ __forceinline__ void split2(float x, unsigned short& hi, unsigned short& lo) {
    hi = bf16_rne(x);
    lo = bf16_rne(x - bf16_tof(hi));
}
__device__ __forceinline__ f32x4 mfma16(short8 a, short8 b, f32x4 c) {
    return __builtin_amdgcn_mfma_f32_16x16x32_bf16(a, b, c, 0, 0, 0);
}
__device__ __forceinline__ short8 neg8(short8 v) {   // flip bf16 sign bits
    union { short8 s; unsigned u[4]; } a; a.s = v;
    a.u[0] ^= 0x80008000u; a.u[1] ^= 0x80008000u;
    a.u[2] ^= 0x80008000u; a.u[3] ^= 0x80008000u;
    return a.s;
}

// ---------------- reductions (256-thread blocks = 4 waves of 64) ----------------
__device__ __forceinline__ float2 blockReduceSum2(float a, float b) {
    __shared__ float smA[4], smB[4];
    for (int o = 32; o > 0; o >>= 1) {
        a += __shfl_down(a, o, 64);
        b += __shfl_down(b, o, 64);
    }
    int wave = threadIdx.x >> 6, lane = threadIdx.x & 63;
    __syncthreads();
    if (lane == 0) { smA[wave] = a; smB[wave] = b; }
    __syncthreads();
    float ra = smA[0] + smA[1] + smA[2] + smA[3];
    float rb = smB[0] + smB[1] + smB[2] + smB[3];
    return make_float2(ra, rb);
}

// ---------------- complex layernorm + fused bf16-split of output ----------------
__global__ void ln_kernel(const float* __restrict__ xr, const float* __restrict__ xi,
                          const float* __restrict__ wr, const float* __restrict__ wi,
                          const float* __restrict__ br, const float* __restrict__ bi,
                          float* __restrict__ outr, float* __restrict__ outi,
                          unsigned short* __restrict__ planes, int S) {
    int row = blockIdx.x;
    int t = threadIdx.x;
    int idx = row * DIM_ + t;
    float xre = xr[idx], xim = xi[idx];
    float2 s = blockReduceSum2(xre, xim);
    float mre = s.x * (1.f / DIM_), mim = s.y * (1.f / DIM_);
    float dr = xre - mre, di = xim - mim;
    float2 v = blockReduceSum2(dr * dr, di * di);
    float c = v.x * (1.f / DIM_) + EPS_;
    float d = v.y * (1.f / DIM_);
    float r = sqrtf(c * c + d * d);
    float sre = sqrtf(0.5f * (r + c));
    float sim = sqrtf(fmaxf(0.5f * (r - c), 0.f));
    float inv = 1.f / r;
    float nr = (dr * sre + di * sim) * inv;
    float ni = (di * sre - dr * sim) * inv;
    float wre = wr[t], wim = wi[t];
    float orr = wre * nr - wim * ni + br[t];
    float oii = wre * ni + wim * nr + bi[t];
    outr[idx] = orr;
    outi[idx] = oii;
    unsigned short rh, rl, ih, il;
    split2(orr, rh, rl);
    split2(oii, ih, il);
    planes[0 * S + idx] = rh;
    planes[1 * S + idx] = rl;
    planes[2 * S + idx] = ih;
    planes[3 * S + idx] = il;
}

// ---------------- weight split: [DEPTH][256x256] cplx -> per-layer 4 planes ----------------
__global__ void wsplit(const float* __restrict__ wr, const float* __restrict__ wi,
                       unsigned short* __restrict__ planes) {
    int idx = blockIdx.x * 256 + threadIdx.x;
    int l = idx >> 16, e = idx & 65535;
    unsigned short rh, rl, ih, il;
    split2(wr[idx], rh, rl);
    split2(wi[idx], ih, il);
    size_t base = (size_t)l * 4 * 65536;
    planes[base + 0 * 65536 + e] = rh;
    planes[base + 1 * 65536 + e] = rl;
    planes[base + 2 * 65536 + e] = ih;
    planes[base + 3 * 65536 + e] = il;
}

// ---------------- MFMA complex GEMM: C[M,256] = A[M,256] x B^T (B[256,256]) ----------------
// MODE 0: write fp32 Cr/Ci.  MODE 1 (QKV): write bf16 split planes of C ([B,N,INNER])
// and of C^T ([B,INNER,N]) for the attention kernel.
template <int MODE>
__global__ __launch_bounds__(64)
void gemm_mfma(const unsigned short* __restrict__ Ap, int aStride,
               const unsigned short* __restrict__ Bp,
               float* __restrict__ Cr, float* __restrict__ Ci,
               unsigned short* __restrict__ wpo, unsigned short* __restrict__ wtpo, int S) {
    const int K = 256;
    int tileN = blockIdx.x * 32, tileM = blockIdx.y * 32;
    int lane = threadIdx.x;
    int m16 = lane & 15, quad = lane >> 4;

    f32x4 accP[2][2], accN[2][2], accI[2][2];
#pragma unroll
    for (int mi = 0; mi < 2; mi++)
#pragma unroll
        for (int ni = 0; ni < 2; ni++) {
            accP[mi][ni] = (f32x4){0.f, 0.f, 0.f, 0.f};
            accN[mi][ni] = (f32x4){0.f, 0.f, 0.f, 0.f};
            accI[mi][ni] = (f32x4){0.f, 0.f, 0.f, 0.f};
        }

#pragma unroll
    for (int k0 = 0; k0 < 256; k0 += 32) {
        int kb = k0 + quad * 8;
        short8 a[4][2], b[4][2];
#pragma unroll
        for (int p = 0; p < 4; p++) {
#pragma unroll
            for (int s = 0; s < 2; s++) {
                a[p][s] = *(const short8*)(Ap + (size_t)p * aStride + (size_t)(tileM + s * 16 + m16) * K + kb);
                b[p][s] = *(const short8*)(Bp + (size_t)p * 65536  + (size_t)(tileN + s * 16 + m16) * K + kb);
            }
        }
#pragma unroll
        for (int mi = 0; mi < 2; mi++)
#pragma unroll
            for (int ni = 0; ni < 2; ni++) {
                f32x4 p1 = accP[mi][ni], p2 = accN[mi][ni], p3 = accI[mi][ni];
                p1 = mfma16(a[0][mi], b[0][ni], p1);
                p1 = mfma16(a[0][mi], b[1][ni], p1);
                p1 = mfma16(a[1][mi], b[0][ni], p1);
                p2 = mfma16(a[2][mi], b[2][ni], p2);
                p2 = mfma16(a[2][mi], b[3][ni], p2);
                p2 = mfma16(a[3][mi], b[2][ni], p2);
                p3 = mfma16(a[0][mi], b[2][ni], p3);
                p3 = mfma16(a[0][mi], b[3][ni], p3);
                p3 = mfma16(a[1][mi], b[2][ni], p3);
                p3 = mfma16(a[2][mi], b[0][ni], p3);
                p3 = mfma16(a[2][mi], b[1][ni], p3);
                p3 = mfma16(a[3][mi], b[0][ni], p3);
                accP[mi][ni] = p1; accN[mi][ni] = p2; accI[mi][ni] = p3;
            }
    }

#pragma unroll
    for (int mi = 0; mi < 2; mi++)
#pragma unroll
        for (int ni = 0; ni < 2; ni++)
#pragma unroll
            for (int r = 0; r < 4; r++) {
                int row = tileM + mi * 16 + quad * 4 + r;
                int col = tileN + ni * 16 + m16;
                float vr = accP[mi][ni][r] - accN[mi][ni][r];
                float vi = accI[mi][ni][r];
                if (MODE == 0) {
                    Cr[row * 256 + col] = vr;
                    Ci[row * 256 + col] = vi;
                } else {
                    unsigned short h0, h1, h2, h3;
                    split2(vr, h0, h1);
                    split2(vi, h2, h3);
                    size_t widx = (size_t)row * 256 + col;
                    size_t tidx = ((size_t)(row >> 10) * 256 + col) * 1024 + (row & 1023);
                    wpo[0 * (size_t)S + widx] = h0;
                    wpo[1 * (size_t)S + widx] = h1;
                    wpo[2 * (size_t)S + widx] = h2;
                    wpo[3 * (size_t)S + widx] = h3;
                    wtpo[0 * (size_t)S + tidx] = h0;
                    wtpo[1 * (size_t)S + tidx] = h1;
                    wtpo[2 * (size_t)S + tidx] = h2;
                    wtpo[3 * (size_t)S + tidx] = h3;
                }
            }
}

// ---------------- MFMA flash attention ----------------
// grid (N/32, B*H), 256 threads. waves: (rowHalf = w&1) x (ktHalf = w>>1).
// Computes S^T = conj(K) Q^T per 16-row Q group (q = lane&15), online softmax on |S|,
// polar P, O^T += V^T P^T. Key-halves merged in LDS. Output written as 4 bf16 planes.
__global__ __launch_bounds__(256, 1)
void attn_mfma(const unsigned short* __restrict__ wp,
               const unsigned short* __restrict__ wtp,
               unsigned short* __restrict__ aop, int S) {
    __shared__ float Pb[4][2112];        // per-wave: P re [0,1056) / P im [1056,2112); reused as merge buf
    __shared__ float mlbuf[2][64][2];

    int tid = threadIdx.x;
    int wave = tid >> 6, lane = tid & 63;
    int m16 = lane & 15, quad = lane >> 4;
    int rowHalf = wave & 1, ktHalf = wave >> 1;
    int zz = blockIdx.y, bb = zz >> 2, hh = zz & 3;
    int q0 = blockIdx.x * 32 + rowHalf * 16;

    // Q fragments (B-side), 4 planes x 2 kchunks, + negated Qr for Si
    short8 qf[4][2], nqr[2][2];
    {
        size_t qbase = (size_t)(bb * N_ + q0 + m16) * INNER_ + hh * DHEAD_;
#pragma unroll
        for (int p = 0; p < 4; p++)
#pragma unroll
            for (int kc = 0; kc < 2; kc++)
                qf[p][kc] = *(const short8*)(wp + (size_t)p * S + qbase + kc * 32 + quad * 8);
        nqr[0][0] = neg8(qf[0][0]); nqr[0][1] = neg8(qf[0][1]);
        nqr[1][0] = neg8(qf[1][0]); nqr[1][1] = neg8(qf[1][1]);
    }

    float mrow = -1e30f, lrow = 0.f;
    f32x4 Oa[4][2];
#pragma unroll
    for (int ni = 0; ni < 4; ni++) { Oa[ni][0] = (f32x4){0,0,0,0}; Oa[ni][1] = (f32x4){0,0,0,0}; }

    float* prb = &Pb[wave][0];
    float* pib = &Pb[wave][1056];

    for (int t = 0; t < 8; t++) {
        int kt = ktHalf + 2 * t;

        // ---- scores S^T[key][q] ----
        f32x4 sr[4], si[4];
#pragma unroll
        for (int ni = 0; ni < 4; ni++) { sr[ni] = (f32x4){0,0,0,0}; si[ni] = (f32x4){0,0,0,0}; }
#pragma unroll
        for (int ni = 0; ni < 4; ni++) {
            size_t kbase = (size_t)(bb * N_ + kt * 64 + ni * 16 + m16) * INNER_ + hh * DHEAD_;
            short8 kf[4][2];
#pragma unroll
            for (int p = 0; p < 4; p++)
#pragma unroll
                for (int kc = 0; kc < 2; kc++)
                    kf[p][kc] = *(const short8*)(wp + (size_t)p * S + kbase + kc * 32 + quad * 8);
#pragma unroll
            for (int kc = 0; kc < 2; kc++) {
                f32x4 r = sr[ni], im = si[ni];
                r  = mfma16(kf[0][kc], qf[0][kc], r);    // KrQr (hh,hl,lh)
                r  = mfma16(kf[0][kc], qf[1][kc], r);
                r  = mfma16(kf[1][kc], qf[0][kc], r);
                r  = mfma16(kf[2][kc], qf[2][kc], r);    // KiQi
                r  = mfma16(kf[2][kc], qf[3][kc], r);
                r  = mfma16(kf[3][kc], qf[2][kc], r);
                im = mfma16(kf[0][kc], qf[2][kc], im);   // KrQi
                im = mfma16(kf[0][kc], qf[3][kc], im);
                im = mfma16(kf[1][kc], qf[2][kc], im);
                im = mfma16(kf[2][kc], nqr[0][kc], im);  // Ki(-Qr)
                im = mfma16(kf[2][kc], nqr[1][kc], im);
                im = mfma16(kf[3][kc], nqr[0][kc], im);
                sr[ni] = r; si[ni] = im;
            }
        }

        // ---- online softmax on |S| (row q = lane&15; reduce across quads) ----
        float mag[4][4], srs[4][4], sis[4][4];
        float mx = -1e30f;
#pragma unroll
        for (int ni = 0; ni < 4; ni++)
#pragma unroll
            for (int r = 0; r < 4; r++) {
                float a = sr[ni][r] * SCALE_, b = si[ni][r] * SCALE_;
                srs[ni][r] = a; sis[ni][r] = b;
                float mg = sqrtf(a * a + b * b);
                mag[ni][r] = mg;
                mx = fmaxf(mx, mg);
            }
        mx = fmaxf(mx, __shfl_xor(mx, 16, 64));
        mx = fmaxf(mx, __shfl_xor(mx, 32, 64));
        float newm = fmaxf(mrow, mx);
        float alpha = expf(mrow - newm);
        mrow = newm;
        float psum = 0.f;
#pragma unroll
        for (int ni = 0; ni < 4; ni++)
#pragma unroll
            for (int r = 0; r < 4; r++) {
                float p = expf(mag[ni][r] - newm);
                psum += p;
                float sc = (mag[ni][r] > 0.f) ? (p / mag[ni][r]) : 0.f;
                float pr = (mag[ni][r] > 0.f) ? srs[ni][r] * sc : p;
                float pi = sis[ni][r] * sc;
                int key = ni * 16 + quad * 4 + r;
                prb[m16 * 66 + key] = pr;
                pib[m16 * 66 + key] = pi;
            }
        psum += __shfl_xor(psum, 16, 64);
        psum += __shfl_xor(psum, 32, 64);
        lrow = lrow * alpha + psum;
#pragma unroll
        for (int ni = 0; ni < 4; ni++)
#pragma unroll
            for (int r = 0; r < 4; r++) { Oa[ni][0][r] *= alpha; Oa[ni][1][r] *= alpha; }

        // ---- P fragments via per-wave LDS transpose (B-side: P[q=lane&15][key]) ----
        short8 prh[2], prl[2], pihf[2], pilf[2], nih[2], nil2[2];
#pragma unroll
        for (int kc = 0; kc < 2; kc++) {
            unsigned short a0[8], a1[8], b0[8], b1[8];
#pragma unroll
            for (int j = 0; j < 8; j++) {
                float vr = prb[m16 * 66 + kc * 32 + quad * 8 + j];
                float vi = pib[m16 * 66 + kc * 32 + quad * 8 + j];
                split2(vr, a0[j], a1[j]);
                split2(vi, b0[j], b1[j]);
            }
            short8 x0, x1, y0, y1;
#pragma unroll
            for (int j = 0; j < 8; j++) {
                x0[j] = (short)a0[j]; x1[j] = (short)a1[j];
                y0[j] = (short)b0[j]; y1[j] = (short)b1[j];
            }
            prh[kc] = x0; prl[kc] = x1; pihf[kc] = y0; pilf[kc] = y1;
            nih[kc] = neg8(y0); nil2[kc] = neg8(y1);
        }

        // ---- O^T += V^T P^T ----
#pragma unroll
        for (int ni = 0; ni < 4; ni++) {
            size_t vbase = (size_t)(bb * INNER_ + hh * DHEAD_ + ni * 16 + m16) * N_ + kt * 64;
            short8 vf[4][2];
#pragma unroll
            for (int p = 0; p < 4; p++)
#pragma unroll
                for (int kc = 0; kc < 2; kc++)
                    vf[p][kc] = *(const short8*)(wtp + (size_t)p * S + vbase + kc * 32 + quad * 8);
#pragma unroll
            for (int kc = 0; kc < 2; kc++) {
                f32x4 orv = Oa[ni][0], oiv = Oa[ni][1];
                orv = mfma16(vf[0][kc], prh[kc], orv);   // VrPr
                orv = mfma16(vf[0][kc], prl[kc], orv);
                orv = mfma16(vf[1][kc], prh[kc], orv);
                orv = mfma16(vf[2][kc], nih[kc], orv);   // Vi(-Pi)
                orv = mfma16(vf[2][kc], nil2[kc], orv);
                orv = mfma16(vf[3][kc], nih[kc], orv);
                oiv = mfma16(vf[0][kc], pihf[kc], oiv);  // VrPi
                oiv = mfma16(vf[0][kc], pilf[kc], oiv);
                oiv = mfma16(vf[1][kc], pihf[kc], oiv);
                oiv = mfma16(vf[2][kc], prh[kc], oiv);   // ViPr
                oiv = mfma16(vf[2][kc], prl[kc], oiv);
                oiv = mfma16(vf[3][kc], prh[kc], oiv);
                Oa[ni][0] = orv; Oa[ni][1] = oiv;
            }
        }
    }

    // ---- merge key-halves (waves 2,3 -> waves 0,1), normalize, store bf16 planes ----
    if (ktHalf == 1) {
        float* mb = &Pb[wave][0];
#pragma unroll
        for (int ni = 0; ni < 4; ni++)
#pragma unroll
            for (int r = 0; r < 4; r++) {
                mb[lane * 33 + ni * 8 + r]     = Oa[ni][0][r];
                mb[lane * 33 + ni * 8 + 4 + r] = Oa[ni][1][r];
            }
        mlbuf[rowHalf][lane][0] = mrow;
        mlbuf[rowHalf][lane][1] = lrow;
    }
    __syncthreads();
    if (ktHalf == 0) {
        float* mb = &Pb[wave + 2][0];
        float m1 = mlbuf[rowHalf][lane][0];
        float l1 = mlbuf[rowHalf][lane][1];
        float mm = fmaxf(mrow, m1);
        float a0 = expf(mrow - mm), a1 = expf(m1 - mm);
        float invl = 1.f / (a0 * lrow + a1 * l1);
        size_t obase = (size_t)(bb * N_ + q0 + m16) * INNER_ + hh * DHEAD_;
#pragma unroll
        for (int ni = 0; ni < 4; ni++)
#pragma unroll
            for (int r = 0; r < 4; r++) {
                float vr = (a0 * Oa[ni][0][r] + a1 * mb[lane * 33 + ni * 8 + r]) * invl;
                float vi = (a0 * Oa[ni][1][r] + a1 * mb[lane * 33 + ni * 8 + 4 + r]) * invl;
                unsigned short h0, h1, h2, h3;
                split2(vr, h0, h1);
                split2(vi, h2, h3);
                size_t o = obase + ni * 16 + quad * 4 + r;
                aop[0 * (size_t)S + o] = h0;
                aop[1 * (size_t)S + o] = h1;
                aop[2 * (size_t)S + o] = h2;
                aop[3 * (size_t)S + o] = h3;
            }
    }
}

// ---------------- epilogues ----------------
__global__ void bias_res(const float* __restrict__ tr, const float* __restrict__ ti,
                         const float* __restrict__ br, const float* __restrict__ bi,
                         float* __restrict__ xr, float* __restrict__ xi) {
    int idx = blockIdx.x * 256 + threadIdx.x;
    int d = idx & (DIM_ - 1);
    xr[idx] = tr[idx] + br[d] + xr[idx];
    xi[idx] = ti[idx] + bi[d] + xi[idx];
}

__global__ void ff_ep(const float* __restrict__ xnr, const float* __restrict__ xni,
                      const float* __restrict__ x1r, const float* __restrict__ x1i,
                      float* __restrict__ xr, float* __restrict__ xi) {
    int idx = blockIdx.x * 256 + threadIdx.x;
    float zr = xnr[idx] + STEP_ * x1r[idx] - STEP_ * LAMBD_;
    float zi = xni[idx] + STEP_ * x1i[idx];
    xr[idx] = fmaxf(zr, 0.f);
    xi[idx] = fmaxf(zi, 0.f);
}

__global__ void pack_planar(const float* __restrict__ xr, const float* __restrict__ xi,
                            float* __restrict__ out, int S, int cap) {
    int idx = blockIdx.x * 256 + threadIdx.x;
    if (idx < cap) out[idx] = xr[idx];
    if (S + idx < cap) out[S + idx] = xi[idx];
}

__global__ void pack_real(const float* __restrict__ xr, float* __restrict__ out, int cap) {
    int idx = blockIdx.x * 256 + threadIdx.x;
    if (idx < cap) out[idx] = xr[idx];
}

// ---------------- host orchestration ----------------
extern "C" void kernel_launch(void* const* d_in, const int* in_sizes, int n_in,
                              void* d_out, int out_size, void* d_ws, size_t ws_size,
                              hipStream_t stream) {
    const float* in_xre = (const float*)d_in[0];
    const float* in_xim = (const float*)d_in[1];
    const float* ln1wr = (const float*)d_in[2];
    const float* ln1wi = (const float*)d_in[3];
    const float* ln1br = (const float*)d_in[4];
    const float* ln1bi = (const float*)d_in[5];
    const float* qkvr  = (const float*)d_in[6];
    const float* qkvi  = (const float*)d_in[7];
    const float* outwr = (const float*)d_in[8];
    const float* outwi = (const float*)d_in[9];
    const float* outbr = (const float*)d_in[10];
    const float* outbi = (const float*)d_in[11];
    const float* ln2wr = (const float*)d_in[12];
    const float* ln2wi = (const float*)d_in[13];
    const float* ln2br = (const float*)d_in[14];
    const float* ln2bi = (const float*)d_in[15];
    const float* ffr   = (const float*)d_in[16];
    const float* ffi   = (const float*)d_in[17];

    const size_t S = (size_t)B_ * N_ * DIM_;          // 524288
    const int    Si = (int)S;

    float* ws  = (float*)d_ws;
    float* xre = ws;            float* xim = xre + S;
    float* xnr = xim + S;       float* xni = xnr + S;
    float* tre = xni + S;       float* tim = tre + S;   // 6*S fp32 = 12 MB

    unsigned short* xnp   = (unsigned short*)(tim + S);        // 4S halves
    unsigned short* aop   = xnp + 4 * S;                       // 4S
    unsigned short* wpb   = aop + 4 * S;                       // 4S (w planes)
    unsigned short* wtpb  = wpb + 4 * S;                       // 4S (w^T planes)
    unsigned short* qkvp  = wtpb + 4 * S;
    unsigned short* outwp = qkvp + (size_t)DEPTH_ * 4 * 65536;
    unsigned short* ffp   = outwp + (size_t)DEPTH_ * 4 * 65536;  // total ~36 MB

    hipMemcpyAsync(xre, in_xre, S * sizeof(float), hipMemcpyDeviceToDevice, stream);
    hipMemcpyAsync(xim, in_xim, S * sizeof(float), hipMemcpyDeviceToDevice, stream);

    wsplit<<<DEPTH_ * 65536 / 256, 256, 0, stream>>>(qkvr, qkvi, qkvp);
    wsplit<<<DEPTH_ * 65536 / 256, 256, 0, stream>>>(outwr, outwi, outwp);
    wsplit<<<DEPTH_ * 65536 / 256, 256, 0, stream>>>(ffr, ffi, ffp);

    const int MR = B_ * N_;
    dim3 gGemm(INNER_ / 32, MR / 32);    // 8 x 64
    dim3 gAttn(N_ / 32, B_ * HEADS_);    // 32 x 8
    int eBlocks = (int)(S / 256);

    for (int l = 0; l < DEPTH_; l++) {
        ln_kernel<<<MR, DIM_, 0, stream>>>(xre, xim,
            ln1wr + l * DIM_, ln1wi + l * DIM_, ln1br + l * DIM_, ln1bi + l * DIM_,
            xnr, xni, xnp, Si);

        // QKV projection -> bf16 split planes of w and w^T
        gemm_mfma<1><<<gGemm, 64, 0, stream>>>(xnp, Si, qkvp + (size_t)l * 4 * 65536,
                                               nullptr, nullptr, wpb, wtpb, Si);

        attn_mfma<<<gAttn, 256, 0, stream>>>(wpb, wtpb, aop, Si);

        gemm_mfma<0><<<gGemm, 64, 0, stream>>>(aop, Si, outwp + (size_t)l * 4 * 65536,
                                               tre, tim, nullptr, nullptr, Si);

        bias_res<<<eBlocks, 256, 0, stream>>>(tre, tim, outbr + l * DIM_, outbi + l * DIM_, xre, xim);

        ln_kernel<<<MR, DIM_, 0, stream>>>(xre, xim,
            ln2wr + l * DIM_, ln2wi + l * DIM_, ln2br + l * DIM_, ln2bi + l * DIM_,
            xnr, xni, xnp, Si);

        gemm_mfma<0><<<gGemm, 64, 0, stream>>>(xnp, Si, ffp + (size_t)l * 4 * 65536,
                                               tre, tim, nullptr, nullptr, Si);

        ff_ep<<<eBlocks, 256, 0, stream>>>(xnr, xni, tre, tim, xre, xim);
    }

    if (out_size >= (int)(2 * S)) {
        pack_planar<<<eBlocks, 256, 0, stream>>>(xre, xim, (float*)d_out, Si, out_size);
    } else {
        pack_real<<<eBlocks, 256, 0, stream>>>(xre, (float*)d_out, out_size);
    }
}

// Round 6
// 667.326 us; speedup vs baseline: 3.1733x; 1.0307x over previous
//
#include <hip/hip_runtime.h>
#include <math.h>

#define B_ 2
#define N_ 1024
#define DIM_ 256
#define DEPTH_ 4
#define HEADS_ 4
#define DHEAD_ 64
#define INNER_ 256
#define SCALE_ 0.125f
#define STEP_ 0.1f
#define LAMBD_ 0.1f
#define EPS_ 1e-5f

typedef __attribute__((ext_vector_type(8))) short short8;
typedef __attribute__((ext_vector_type(4))) float f32x4;

// ---------------- bf16 split helpers ----------------
__device__ __forceinline__ unsigned short bf16_rne(float x) {
    unsigned u = __float_as_uint(x);
    unsigned r = (u + 0x7FFFu + ((u >> 16) & 1u)) >> 16;
    return (unsigned short)r;
}
__device__ __forceinline__ float bf16_tof(unsigned short h) {
    return __uint_as_float(((unsigned)h) << 16);
}
__device__ __forceinline__ void split2(float x, unsigned short& hi, unsigned short& lo) {
    hi = bf16_rne(x);
    lo = bf16_rne(x - bf16_tof(hi));
}
__device__ __forceinline__ f32x4 mfma16(short8 a, short8 b, f32x4 c) {
    return __builtin_amdgcn_mfma_f32_16x16x32_bf16(a, b, c, 0, 0, 0);
}
__device__ __forceinline__ short8 neg8(short8 v) {
    union { short8 s; unsigned u[4]; } a; a.s = v;
    a.u[0] ^= 0x80008000u; a.u[1] ^= 0x80008000u;
    a.u[2] ^= 0x80008000u; a.u[3] ^= 0x80008000u;
    return a.s;
}

// ---------------- reductions (256-thread blocks = 4 waves of 64) ----------------
__device__ __forceinline__ float2 blockReduceSum2(float a, float b) {
    __shared__ float smA[4], smB[4];
    for (int o = 32; o > 0; o >>= 1) {
        a += __shfl_down(a, o, 64);
        b += __shfl_down(b, o, 64);
    }
    int wave = threadIdx.x >> 6, lane = threadIdx.x & 63;
    __syncthreads();
    if (lane == 0) { smA[wave] = a; smB[wave] = b; }
    __syncthreads();
    float ra = smA[0] + smA[1] + smA[2] + smA[3];
    float rb = smB[0] + smB[1] + smB[2] + smB[3];
    return make_float2(ra, rb);
}

// ---------------- complex layernorm + fused bf16-split of output ----------------
__global__ void ln_kernel(const float* __restrict__ xr, const float* __restrict__ xi,
                          const float* __restrict__ wr, const float* __restrict__ wi,
                          const float* __restrict__ br, const float* __restrict__ bi,
                          float* __restrict__ outr, float* __restrict__ outi,
                          unsigned short* __restrict__ planes, int S) {
    int row = blockIdx.x;
    int t = threadIdx.x;
    int idx = row * DIM_ + t;
    float xre = xr[idx], xim = xi[idx];
    float2 s = blockReduceSum2(xre, xim);
    float mre = s.x * (1.f / DIM_), mim = s.y * (1.f / DIM_);
    float dr = xre - mre, di = xim - mim;
    float2 v = blockReduceSum2(dr * dr, di * di);
    float c = v.x * (1.f / DIM_) + EPS_;
    float d = v.y * (1.f / DIM_);
    float r = sqrtf(c * c + d * d);
    float sre = sqrtf(0.5f * (r + c));
    float sim = sqrtf(fmaxf(0.5f * (r - c), 0.f));
    float inv = 1.f / r;
    float nr = (dr * sre + di * sim) * inv;
    float ni = (di * sre - dr * sim) * inv;
    float wre = wr[t], wim = wi[t];
    float orr = wre * nr - wim * ni + br[t];
    float oii = wre * ni + wim * nr + bi[t];
    outr[idx] = orr;
    outi[idx] = oii;
    unsigned short rh, rl, ih, il;
    split2(orr, rh, rl);
    split2(oii, ih, il);
    planes[0 * S + idx] = rh;
    planes[1 * S + idx] = rl;
    planes[2 * S + idx] = ih;
    planes[3 * S + idx] = il;
}

// ---------------- weight split ----------------
__global__ void wsplit(const float* __restrict__ wr, const float* __restrict__ wi,
                       unsigned short* __restrict__ planes) {
    int idx = blockIdx.x * 256 + threadIdx.x;
    int l = idx >> 16, e = idx & 65535;
    unsigned short rh, rl, ih, il;
    split2(wr[idx], rh, rl);
    split2(wi[idx], ih, il);
    size_t base = (size_t)l * 4 * 65536;
    planes[base + 0 * 65536 + e] = rh;
    planes[base + 1 * 65536 + e] = rl;
    planes[base + 2 * 65536 + e] = ih;
    planes[base + 3 * 65536 + e] = il;
}

// ---------------- MFMA complex GEMM, 16x16 tile, 1 wave/block ----------------
// C[M,256] = A[M,256] x B^T.  MODE 1: QKV -> bf16 planes of w and w^T.
// MODE 2: out-proj -> xo = C + bias + res (residual add fused).
// MODE 3: FF -> xo = CReLU(res + STEP*C - STEP*LAMBD)   (res = xn here).
template <int MODE>
__global__ __launch_bounds__(64)
void gemm_mfma(const unsigned short* __restrict__ Ap, int aStride,
               const unsigned short* __restrict__ Bp,
               unsigned short* __restrict__ wpo, unsigned short* __restrict__ wtpo,
               const float* __restrict__ biasR, const float* __restrict__ biasI,
               const float* resR, const float* resI,
               float* xoR, float* xoI, int S) {
    const int K = 256;
    int tileN = blockIdx.x * 16, tileM = blockIdx.y * 16;
    int lane = threadIdx.x;
    int m16 = lane & 15, quad = lane >> 4;

    f32x4 accP = (f32x4){0,0,0,0}, accN = (f32x4){0,0,0,0};
    f32x4 accIa = (f32x4){0,0,0,0}, accIb = (f32x4){0,0,0,0};

#pragma unroll
    for (int k0 = 0; k0 < 256; k0 += 32) {
        int kb = k0 + quad * 8;
        short8 a[4], b[4];
#pragma unroll
        for (int p = 0; p < 4; p++) {
            a[p] = *(const short8*)(Ap + (size_t)p * aStride + (size_t)(tileM + m16) * K + kb);
            b[p] = *(const short8*)(Bp + (size_t)p * 65536  + (size_t)(tileN + m16) * K + kb);
        }
        accP  = mfma16(a[0], b[0], accP);
        accP  = mfma16(a[0], b[1], accP);
        accP  = mfma16(a[1], b[0], accP);
        accN  = mfma16(a[2], b[2], accN);
        accN  = mfma16(a[2], b[3], accN);
        accN  = mfma16(a[3], b[2], accN);
        accIa = mfma16(a[0], b[2], accIa);
        accIa = mfma16(a[0], b[3], accIa);
        accIa = mfma16(a[1], b[2], accIa);
        accIb = mfma16(a[2], b[0], accIb);
        accIb = mfma16(a[2], b[1], accIb);
        accIb = mfma16(a[3], b[0], accIb);
    }

#pragma unroll
    for (int r = 0; r < 4; r++) {
        int row = tileM + quad * 4 + r;
        int col = tileN + m16;
        size_t g = (size_t)row * 256 + col;
        float vr = accP[r] - accN[r];
        float vi = accIa[r] + accIb[r];
        if (MODE == 1) {
            unsigned short h0, h1, h2, h3;
            split2(vr, h0, h1);
            split2(vi, h2, h3);
            size_t tidx = ((size_t)(row >> 10) * 256 + col) * 1024 + (row & 1023);
            wpo[0 * (size_t)S + g] = h0;
            wpo[1 * (size_t)S + g] = h1;
            wpo[2 * (size_t)S + g] = h2;
            wpo[3 * (size_t)S + g] = h3;
            wtpo[0 * (size_t)S + tidx] = h0;
            wtpo[1 * (size_t)S + tidx] = h1;
            wtpo[2 * (size_t)S + tidx] = h2;
            wtpo[3 * (size_t)S + tidx] = h3;
        } else if (MODE == 2) {
            xoR[g] = vr + biasR[col] + resR[g];
            xoI[g] = vi + biasI[col] + resI[g];
        } else {
            float zr = resR[g] + STEP_ * vr - STEP_ * LAMBD_;
            float zi = resI[g] + STEP_ * vi;
            xoR[g] = fmaxf(zr, 0.f);
            xoI[g] = fmaxf(zi, 0.f);
        }
    }
}

// ---------------- MFMA flash attention, 4-way key split across waves ----------------
// grid (N/16, B*H) = (64, 8) -> 512 blocks (2 blocks/CU). 256 threads.
// All 4 waves share the same 16 Q rows; wave w handles key tiles kt = w + 4*t.
// S^T = conj(K) Q^T  (q = lane&15), online softmax on |S|, polar P, O^T += V^T P^T.
// 4-way merge of (m, l, O) in LDS at the end; output as 4 bf16 planes.
__global__ __launch_bounds__(256, 2)
void attn_mfma(const unsigned short* __restrict__ wp,
               const unsigned short* __restrict__ wtp,
               unsigned short* __restrict__ aop, int S) {
    __shared__ float Pb[4][2112];       // per-wave P re/im; reused as merge buffer
    __shared__ float mlbuf[4][64][2];

    int tid = threadIdx.x;
    int wave = tid >> 6, lane = tid & 63;
    int m16 = lane & 15, quad = lane >> 4;
    int zz = blockIdx.y, bb = zz >> 2, hh = zz & 3;
    int q0 = blockIdx.x * 16;

    // Q fragments (B-side), shared across waves
    short8 qf[4][2], nqr[2][2];
    {
        size_t qbase = (size_t)(bb * N_ + q0 + m16) * INNER_ + hh * DHEAD_;
#pragma unroll
        for (int p = 0; p < 4; p++)
#pragma unroll
            for (int kc = 0; kc < 2; kc++)
                qf[p][kc] = *(const short8*)(wp + (size_t)p * S + qbase + kc * 32 + quad * 8);
        nqr[0][0] = neg8(qf[0][0]); nqr[0][1] = neg8(qf[0][1]);
        nqr[1][0] = neg8(qf[1][0]); nqr[1][1] = neg8(qf[1][1]);
    }

    float mrow = -1e30f, lrow = 0.f;
    f32x4 Oa[4][2];
#pragma unroll
    for (int ni = 0; ni < 4; ni++) { Oa[ni][0] = (f32x4){0,0,0,0}; Oa[ni][1] = (f32x4){0,0,0,0}; }

    float* prb = &Pb[wave][0];
    float* pib = &Pb[wave][1056];

    for (int t = 0; t < 4; t++) {
        int kt = wave + 4 * t;

        // ---- scores S^T[key][q] ----
        f32x4 sr[4], si[4];
#pragma unroll
        for (int ni = 0; ni < 4; ni++) { sr[ni] = (f32x4){0,0,0,0}; si[ni] = (f32x4){0,0,0,0}; }
#pragma unroll
        for (int ni = 0; ni < 4; ni++) {
            size_t kbase = (size_t)(bb * N_ + kt * 64 + ni * 16 + m16) * INNER_ + hh * DHEAD_;
            short8 kf[4][2];
#pragma unroll
            for (int p = 0; p < 4; p++)
#pragma unroll
                for (int kc = 0; kc < 2; kc++)
                    kf[p][kc] = *(const short8*)(wp + (size_t)p * S + kbase + kc * 32 + quad * 8);
#pragma unroll
            for (int kc = 0; kc < 2; kc++) {
                f32x4 r = sr[ni], im = si[ni];
                r  = mfma16(kf[0][kc], qf[0][kc], r);
                r  = mfma16(kf[0][kc], qf[1][kc], r);
                r  = mfma16(kf[1][kc], qf[0][kc], r);
                r  = mfma16(kf[2][kc], qf[2][kc], r);
                r  = mfma16(kf[2][kc], qf[3][kc], r);
                r  = mfma16(kf[3][kc], qf[2][kc], r);
                im = mfma16(kf[0][kc], qf[2][kc], im);
                im = mfma16(kf[0][kc], qf[3][kc], im);
                im = mfma16(kf[1][kc], qf[2][kc], im);
                im = mfma16(kf[2][kc], nqr[0][kc], im);
                im = mfma16(kf[2][kc], nqr[1][kc], im);
                im = mfma16(kf[3][kc], nqr[0][kc], im);
                sr[ni] = r; si[ni] = im;
            }
        }

        // ---- online softmax on |S| ----
        float mag[4][4], srs[4][4], sis[4][4];
        float mx = -1e30f;
#pragma unroll
        for (int ni = 0; ni < 4; ni++)
#pragma unroll
            for (int r = 0; r < 4; r++) {
                float a = sr[ni][r] * SCALE_, b = si[ni][r] * SCALE_;
                srs[ni][r] = a; sis[ni][r] = b;
                float mg = sqrtf(a * a + b * b);
                mag[ni][r] = mg;
                mx = fmaxf(mx, mg);
            }
        mx = fmaxf(mx, __shfl_xor(mx, 16, 64));
        mx = fmaxf(mx, __shfl_xor(mx, 32, 64));
        float newm = fmaxf(mrow, mx);
        float alpha = expf(mrow - newm);
        mrow = newm;
        float psum = 0.f;
#pragma unroll
        for (int ni = 0; ni < 4; ni++)
#pragma unroll
            for (int r = 0; r < 4; r++) {
                float p = expf(mag[ni][r] - newm);
                psum += p;
                float sc = (mag[ni][r] > 0.f) ? (p / mag[ni][r]) : 0.f;
                float pr = (mag[ni][r] > 0.f) ? srs[ni][r] * sc : p;
                float pi = sis[ni][r] * sc;
                int key = ni * 16 + quad * 4 + r;
                prb[m16 * 66 + key] = pr;
                pib[m16 * 66 + key] = pi;
            }
        psum += __shfl_xor(psum, 16, 64);
        psum += __shfl_xor(psum, 32, 64);
        lrow = lrow * alpha + psum;
#pragma unroll
        for (int ni = 0; ni < 4; ni++)
#pragma unroll
            for (int r = 0; r < 4; r++) { Oa[ni][0][r] *= alpha; Oa[ni][1][r] *= alpha; }

        // ---- P fragments via per-wave LDS transpose ----
        short8 prh[2], prl[2], pihf[2], pilf[2], nih[2], nil2[2];
#pragma unroll
        for (int kc = 0; kc < 2; kc++) {
            unsigned short a0[8], a1[8], b0[8], b1[8];
#pragma unroll
            for (int j = 0; j < 8; j++) {
                float vr = prb[m16 * 66 + kc * 32 + quad * 8 + j];
                float vi = pib[m16 * 66 + kc * 32 + quad * 8 + j];
                split2(vr, a0[j], a1[j]);
                split2(vi, b0[j], b1[j]);
            }
            short8 x0, x1, y0, y1;
#pragma unroll
            for (int j = 0; j < 8; j++) {
                x0[j] = (short)a0[j]; x1[j] = (short)a1[j];
                y0[j] = (short)b0[j]; y1[j] = (short)b1[j];
            }
            prh[kc] = x0; prl[kc] = x1; pihf[kc] = y0; pilf[kc] = y1;
            nih[kc] = neg8(y0); nil2[kc] = neg8(y1);
        }

        // ---- O^T += V^T P^T ----
#pragma unroll
        for (int ni = 0; ni < 4; ni++) {
            size_t vbase = (size_t)(bb * INNER_ + hh * DHEAD_ + ni * 16 + m16) * N_ + kt * 64;
            short8 vf[4][2];
#pragma unroll
            for (int p = 0; p < 4; p++)
#pragma unroll
                for (int kc = 0; kc < 2; kc++)
                    vf[p][kc] = *(const short8*)(wtp + (size_t)p * S + vbase + kc * 32 + quad * 8);
#pragma unroll
            for (int kc = 0; kc < 2; kc++) {
                f32x4 orv = Oa[ni][0], oiv = Oa[ni][1];
                orv = mfma16(vf[0][kc], prh[kc], orv);
                orv = mfma16(vf[0][kc], prl[kc], orv);
                orv = mfma16(vf[1][kc], prh[kc], orv);
                orv = mfma16(vf[2][kc], nih[kc], orv);
                orv = mfma16(vf[2][kc], nil2[kc], orv);
                orv = mfma16(vf[3][kc], nih[kc], orv);
                oiv = mfma16(vf[0][kc], pihf[kc], oiv);
                oiv = mfma16(vf[0][kc], pilf[kc], oiv);
                oiv = mfma16(vf[1][kc], pihf[kc], oiv);
                oiv = mfma16(vf[2][kc], prh[kc], oiv);
                oiv = mfma16(vf[2][kc], prl[kc], oiv);
                oiv = mfma16(vf[3][kc], prh[kc], oiv);
                Oa[ni][0] = orv; Oa[ni][1] = oiv;
            }
        }
    }

    // ---- 4-way merge across waves ----
    if (wave != 0) {
        float* mb = &Pb[wave][0];
#pragma unroll
        for (int ni = 0; ni < 4; ni++)
#pragma unroll
            for (int r = 0; r < 4; r++) {
                mb[lane * 33 + ni * 8 + r]     = Oa[ni][0][r];
                mb[lane * 33 + ni * 8 + 4 + r] = Oa[ni][1][r];
            }
        mlbuf[wave][lane][0] = mrow;
        mlbuf[wave][lane][1] = lrow;
    }
    __syncthreads();
    if (wave == 0) {
        float mm = mrow;
#pragma unroll
        for (int w = 1; w < 4; w++) mm = fmaxf(mm, mlbuf[w][lane][0]);
        float a0 = expf(mrow - mm);
        float ltot = a0 * lrow;
        float aw[3];
#pragma unroll
        for (int w = 1; w < 4; w++) {
            aw[w - 1] = expf(mlbuf[w][lane][0] - mm);
            ltot += aw[w - 1] * mlbuf[w][lane][1];
        }
        float invl = 1.f / ltot;
        size_t obase = (size_t)(bb * N_ + q0 + m16) * INNER_ + hh * DHEAD_;
#pragma unroll
        for (int ni = 0; ni < 4; ni++)
#pragma unroll
            for (int r = 0; r < 4; r++) {
                float vr = a0 * Oa[ni][0][r];
                float vi = a0 * Oa[ni][1][r];
#pragma unroll
                for (int w = 1; w < 4; w++) {
                    vr += aw[w - 1] * Pb[w][lane * 33 + ni * 8 + r];
                    vi += aw[w - 1] * Pb[w][lane * 33 + ni * 8 + 4 + r];
                }
                vr *= invl; vi *= invl;
                unsigned short h0, h1, h2, h3;
                split2(vr, h0, h1);
                split2(vi, h2, h3);
                size_t o = obase + ni * 16 + quad * 4 + r;
                aop[0 * (size_t)S + o] = h0;
                aop[1 * (size_t)S + o] = h1;
                aop[2 * (size_t)S + o] = h2;
                aop[3 * (size_t)S + o] = h3;
            }
    }
}

// ---------------- output pack ----------------
__global__ void pack_planar(const float* __restrict__ xr, const float* __restrict__ xi,
                            float* __restrict__ out, int S, int cap) {
    int idx = blockIdx.x * 256 + threadIdx.x;
    if (idx < cap) out[idx] = xr[idx];
    if (S + idx < cap) out[S + idx] = xi[idx];
}

__global__ void pack_real(const float* __restrict__ xr, float* __restrict__ out, int cap) {
    int idx = blockIdx.x * 256 + threadIdx.x;
    if (idx < cap) out[idx] = xr[idx];
}

// ---------------- host orchestration ----------------
extern "C" void kernel_launch(void* const* d_in, const int* in_sizes, int n_in,
                              void* d_out, int out_size, void* d_ws, size_t ws_size,
                              hipStream_t stream) {
    const float* in_xre = (const float*)d_in[0];
    const float* in_xim = (const float*)d_in[1];
    const float* ln1wr = (const float*)d_in[2];
    const float* ln1wi = (const float*)d_in[3];
    const float* ln1br = (const float*)d_in[4];
    const float* ln1bi = (const float*)d_in[5];
    const float* qkvr  = (const float*)d_in[6];
    const float* qkvi  = (const float*)d_in[7];
    const float* outwr = (const float*)d_in[8];
    const float* outwi = (const float*)d_in[9];
    const float* outbr = (const float*)d_in[10];
    const float* outbi = (const float*)d_in[11];
    const float* ln2wr = (const float*)d_in[12];
    const float* ln2wi = (const float*)d_in[13];
    const float* ln2br = (const float*)d_in[14];
    const float* ln2bi = (const float*)d_in[15];
    const float* ffr   = (const float*)d_in[16];
    const float* ffi   = (const float*)d_in[17];

    const size_t S = (size_t)B_ * N_ * DIM_;          // 524288
    const int    Si = (int)S;

    float* ws  = (float*)d_ws;
    float* xre = ws;            float* xim = xre + S;
    float* xnr = xim + S;       float* xni = xnr + S;   // 4*S fp32 = 8 MB

    unsigned short* xnp   = (unsigned short*)(xni + S);        // 4S u16
    unsigned short* aop   = xnp + 4 * S;
    unsigned short* wpb   = aop + 4 * S;
    unsigned short* wtpb  = wpb + 4 * S;                       // 16 MB
    unsigned short* qkvp  = wtpb + 4 * S;
    unsigned short* outwp = qkvp + (size_t)DEPTH_ * 4 * 65536;
    unsigned short* ffp   = outwp + (size_t)DEPTH_ * 4 * 65536; // ~30 MB total

    wsplit<<<DEPTH_ * 65536 / 256, 256, 0, stream>>>(qkvr, qkvi, qkvp);
    wsplit<<<DEPTH_ * 65536 / 256, 256, 0, stream>>>(outwr, outwi, outwp);
    wsplit<<<DEPTH_ * 65536 / 256, 256, 0, stream>>>(ffr, ffi, ffp);

    const int MR = B_ * N_;
    dim3 gGemm(INNER_ / 16, MR / 16);    // 16 x 128 = 2048 single-wave blocks
    dim3 gAttn(N_ / 16, B_ * HEADS_);    // 64 x 8 = 512 blocks
    int eBlocks = (int)(S / 256);

    for (int l = 0; l < DEPTH_; l++) {
        const float* xinR = (l == 0) ? in_xre : xre;
        const float* xinI = (l == 0) ? in_xim : xim;

        // LN1 (reads input directly on layer 0)
        ln_kernel<<<MR, DIM_, 0, stream>>>(xinR, xinI,
            ln1wr + l * DIM_, ln1wi + l * DIM_, ln1br + l * DIM_, ln1bi + l * DIM_,
            xnr, xni, xnp, Si);

        // QKV projection -> bf16 split planes of w and w^T
        gemm_mfma<1><<<gGemm, 64, 0, stream>>>(xnp, Si, qkvp + (size_t)l * 4 * 65536,
            wpb, wtpb, nullptr, nullptr, nullptr, nullptr, nullptr, nullptr, Si);

        attn_mfma<<<gAttn, 256, 0, stream>>>(wpb, wtpb, aop, Si);

        // out-proj + bias + residual -> x
        gemm_mfma<2><<<gGemm, 64, 0, stream>>>(aop, Si, outwp + (size_t)l * 4 * 65536,
            nullptr, nullptr, outbr + l * DIM_, outbi + l * DIM_, xinR, xinI, xre, xim, Si);

        // LN2
        ln_kernel<<<MR, DIM_, 0, stream>>>(xre, xim,
            ln2wr + l * DIM_, ln2wi + l * DIM_, ln2br + l * DIM_, ln2bi + l * DIM_,
            xnr, xni, xnp, Si);

        // FF + CReLU epilogue -> x
        gemm_mfma<3><<<gGemm, 64, 0, stream>>>(xnp, Si, ffp + (size_t)l * 4 * 65536,
            nullptr, nullptr, nullptr, nullptr, xnr, xni, xre, xim, Si);
    }

    if (out_size >= (int)(2 * S)) {
        pack_planar<<<eBlocks, 256, 0, stream>>>(xre, xim, (float*)d_out, Si, out_size);
    } else {
        pack_real<<<eBlocks, 256, 0, stream>>>(xre, (float*)d_out, out_size);
    }
}

// Round 7
// 655.606 us; speedup vs baseline: 3.2300x; 1.0179x over previous
//
#include <hip/hip_runtime.h>
#include <math.h>

#define B_ 2
#define N_ 1024
#define DIM_ 256
#define DEPTH_ 4
#define HEADS_ 4
#define DHEAD_ 64
#define INNER_ 256
#define SCALE_ 0.125f
#define STEP_ 0.1f
#define LAMBD_ 0.1f
#define EPS_ 1e-5f

typedef __attribute__((ext_vector_type(8))) short short8;
typedef __attribute__((ext_vector_type(4))) float f32x4;

// ---------------- bf16 split helpers ----------------
__device__ __forceinline__ unsigned short bf16_rne(float x) {
    unsigned u = __float_as_uint(x);
    unsigned r = (u + 0x7FFFu + ((u >> 16) & 1u)) >> 16;
    return (unsigned short)r;
}
__device__ __forceinline__ float bf16_tof(unsigned short h) {
    return __uint_as_float(((unsigned)h) << 16);
}
__device__ __forceinline__ void split2(float x, unsigned short& hi, unsigned short& lo) {
    hi = bf16_rne(x);
    lo = bf16_rne(x - bf16_tof(hi));
}
__device__ __forceinline__ f32x4 mfma16(short8 a, short8 b, f32x4 c) {
    return __builtin_amdgcn_mfma_f32_16x16x32_bf16(a, b, c, 0, 0, 0);
}
__device__ __forceinline__ short8 neg8(short8 v) {
    union { short8 s; unsigned u[4]; } a; a.s = v;
    a.u[0] ^= 0x80008000u; a.u[1] ^= 0x80008000u;
    a.u[2] ^= 0x80008000u; a.u[3] ^= 0x80008000u;
    return a.s;
}

// ---------------- reductions (256-thread blocks = 4 waves of 64) ----------------
__device__ __forceinline__ float2 blockReduceSum2(float a, float b) {
    __shared__ float smA[4], smB[4];
    for (int o = 32; o > 0; o >>= 1) {
        a += __shfl_down(a, o, 64);
        b += __shfl_down(b, o, 64);
    }
    int wave = threadIdx.x >> 6, lane = threadIdx.x & 63;
    __syncthreads();
    if (lane == 0) { smA[wave] = a; smB[wave] = b; }
    __syncthreads();
    float ra = smA[0] + smA[1] + smA[2] + smA[3];
    float rb = smB[0] + smB[1] + smB[2] + smB[3];
    return make_float2(ra, rb);
}

// ---------------- complex layernorm + fused bf16-split of output ----------------
__global__ void ln_kernel(const float* __restrict__ xr, const float* __restrict__ xi,
                          const float* __restrict__ wr, const float* __restrict__ wi,
                          const float* __restrict__ br, const float* __restrict__ bi,
                          float* __restrict__ outr, float* __restrict__ outi,
                          unsigned short* __restrict__ planes, int S) {
    int row = blockIdx.x;
    int t = threadIdx.x;
    int idx = row * DIM_ + t;
    float xre = xr[idx], xim = xi[idx];
    float2 s = blockReduceSum2(xre, xim);
    float mre = s.x * (1.f / DIM_), mim = s.y * (1.f / DIM_);
    float dr = xre - mre, di = xim - mim;
    float2 v = blockReduceSum2(dr * dr, di * di);
    float c = v.x * (1.f / DIM_) + EPS_;
    float d = v.y * (1.f / DIM_);
    float r = sqrtf(c * c + d * d);
    float sre = sqrtf(0.5f * (r + c));
    float sim = sqrtf(fmaxf(0.5f * (r - c), 0.f));
    float inv = 1.f / r;
    float nr = (dr * sre + di * sim) * inv;
    float ni = (di * sre - dr * sim) * inv;
    float wre = wr[t], wim = wi[t];
    float orr = wre * nr - wim * ni + br[t];
    float oii = wre * ni + wim * nr + bi[t];
    outr[idx] = orr;
    outi[idx] = oii;
    unsigned short rh, rl, ih, il;
    split2(orr, rh, rl);
    split2(oii, ih, il);
    planes[0 * S + idx] = rh;
    planes[1 * S + idx] = rl;
    planes[2 * S + idx] = ih;
    planes[3 * S + idx] = il;
}

// ---------------- weight split ----------------
__global__ void wsplit(const float* __restrict__ wr, const float* __restrict__ wi,
                       unsigned short* __restrict__ planes) {
    int idx = blockIdx.x * 256 + threadIdx.x;
    int l = idx >> 16, e = idx & 65535;
    unsigned short rh, rl, ih, il;
    split2(wr[idx], rh, rl);
    split2(wi[idx], ih, il);
    size_t base = (size_t)l * 4 * 65536;
    planes[base + 0 * 65536 + e] = rh;
    planes[base + 1 * 65536 + e] = rl;
    planes[base + 2 * 65536 + e] = ih;
    planes[base + 3 * 65536 + e] = il;
}

// ---------------- MFMA complex GEMM, 16x16 tile, 1 wave/block ----------------
// grid (M/16, 256/16): blockIdx.x = M-tile (fast dim -> XCD spread over rows,
// A-tile L2-local per XCD, B fully replicated but only 512 KB).
// MODE 1: QKV -> bf16 planes of w and w^T.
// MODE 2: out-proj -> xo = C + bias + res.
// MODE 3: FF -> xo = CReLU(res + STEP*C - STEP*LAMBD)  (res = xn).
template <int MODE>
__global__ __launch_bounds__(64)
void gemm_mfma(const unsigned short* __restrict__ Ap, int aStride,
               const unsigned short* __restrict__ Bp,
               unsigned short* __restrict__ wpo, unsigned short* __restrict__ wtpo,
               const float* __restrict__ biasR, const float* __restrict__ biasI,
               const float* resR, const float* resI,
               float* xoR, float* xoI, int S) {
    const int K = 256;
    int tileM = blockIdx.x * 16, tileN = blockIdx.y * 16;
    int lane = threadIdx.x;
    int m16 = lane & 15, quad = lane >> 4;

    f32x4 accP = (f32x4){0,0,0,0}, accN = (f32x4){0,0,0,0};
    f32x4 accIa = (f32x4){0,0,0,0}, accIb = (f32x4){0,0,0,0};

#pragma unroll
    for (int k0 = 0; k0 < 256; k0 += 32) {
        int kb = k0 + quad * 8;
        short8 a[4], b[4];
#pragma unroll
        for (int p = 0; p < 4; p++) {
            a[p] = *(const short8*)(Ap + (size_t)p * aStride + (size_t)(tileM + m16) * K + kb);
            b[p] = *(const short8*)(Bp + (size_t)p * 65536  + (size_t)(tileN + m16) * K + kb);
        }
        accP  = mfma16(a[0], b[0], accP);
        accP  = mfma16(a[0], b[1], accP);
        accP  = mfma16(a[1], b[0], accP);
        accN  = mfma16(a[2], b[2], accN);
        accN  = mfma16(a[2], b[3], accN);
        accN  = mfma16(a[3], b[2], accN);
        accIa = mfma16(a[0], b[2], accIa);
        accIa = mfma16(a[0], b[3], accIa);
        accIa = mfma16(a[1], b[2], accIa);
        accIb = mfma16(a[2], b[0], accIb);
        accIb = mfma16(a[2], b[1], accIb);
        accIb = mfma16(a[3], b[0], accIb);
    }

#pragma unroll
    for (int r = 0; r < 4; r++) {
        int row = tileM + quad * 4 + r;
        int col = tileN + m16;
        size_t g = (size_t)row * 256 + col;
        float vr = accP[r] - accN[r];
        float vi = accIa[r] + accIb[r];
        if (MODE == 1) {
            unsigned short h0, h1, h2, h3;
            split2(vr, h0, h1);
            split2(vi, h2, h3);
            size_t tidx = ((size_t)(row >> 10) * 256 + col) * 1024 + (row & 1023);
            wpo[0 * (size_t)S + g] = h0;
            wpo[1 * (size_t)S + g] = h1;
            wpo[2 * (size_t)S + g] = h2;
            wpo[3 * (size_t)S + g] = h3;
            wtpo[0 * (size_t)S + tidx] = h0;
            wtpo[1 * (size_t)S + tidx] = h1;
            wtpo[2 * (size_t)S + tidx] = h2;
            wtpo[3 * (size_t)S + tidx] = h3;
        } else if (MODE == 2) {
            xoR[g] = vr + biasR[col] + resR[g];
            xoI[g] = vi + biasI[col] + resI[g];
        } else {
            float zr = resR[g] + STEP_ * vr - STEP_ * LAMBD_;
            float zi = resI[g] + STEP_ * vi;
            xoR[g] = fmaxf(zr, 0.f);
            xoI[g] = fmaxf(zi, 0.f);
        }
    }
}

// ---------------- MFMA flash attention, 4-way key split across waves ----------------
// grid (B*H, N/16) = (8, 64): blockIdx.x = (b,h) -> all 64 Q-blocks of one head
// land on one XCD (round-robin linear dispatch), K/V planes L2-resident.
// 256 threads; wave w handles key tiles kt = w + 4*t.
__global__ __launch_bounds__(256, 2)
void attn_mfma(const unsigned short* __restrict__ wp,
               const unsigned short* __restrict__ wtp,
               unsigned short* __restrict__ aop, int S) {
    __shared__ float Pb[4][2112];
    __shared__ float mlbuf[4][64][2];

    int tid = threadIdx.x;
    int wave = tid >> 6, lane = tid & 63;
    int m16 = lane & 15, quad = lane >> 4;
    int zz = blockIdx.x, bb = zz >> 2, hh = zz & 3;
    int q0 = blockIdx.y * 16;

    short8 qf[4][2], nqr[2][2];
    {
        size_t qbase = (size_t)(bb * N_ + q0 + m16) * INNER_ + hh * DHEAD_;
#pragma unroll
        for (int p = 0; p < 4; p++)
#pragma unroll
            for (int kc = 0; kc < 2; kc++)
                qf[p][kc] = *(const short8*)(wp + (size_t)p * S + qbase + kc * 32 + quad * 8);
        nqr[0][0] = neg8(qf[0][0]); nqr[0][1] = neg8(qf[0][1]);
        nqr[1][0] = neg8(qf[1][0]); nqr[1][1] = neg8(qf[1][1]);
    }

    float mrow = -1e30f, lrow = 0.f;
    f32x4 Oa[4][2];
#pragma unroll
    for (int ni = 0; ni < 4; ni++) { Oa[ni][0] = (f32x4){0,0,0,0}; Oa[ni][1] = (f32x4){0,0,0,0}; }

    float* prb = &Pb[wave][0];
    float* pib = &Pb[wave][1056];

    for (int t = 0; t < 4; t++) {
        int kt = wave + 4 * t;

        // ---- scores S^T[key][q] ----
        f32x4 sr[4], si[4];
#pragma unroll
        for (int ni = 0; ni < 4; ni++) { sr[ni] = (f32x4){0,0,0,0}; si[ni] = (f32x4){0,0,0,0}; }
#pragma unroll
        for (int ni = 0; ni < 4; ni++) {
            size_t kbase = (size_t)(bb * N_ + kt * 64 + ni * 16 + m16) * INNER_ + hh * DHEAD_;
            short8 kf[4][2];
#pragma unroll
            for (int p = 0; p < 4; p++)
#pragma unroll
                for (int kc = 0; kc < 2; kc++)
                    kf[p][kc] = *(const short8*)(wp + (size_t)p * S + kbase + kc * 32 + quad * 8);
#pragma unroll
            for (int kc = 0; kc < 2; kc++) {
                f32x4 r = sr[ni], im = si[ni];
                r  = mfma16(kf[0][kc], qf[0][kc], r);
                r  = mfma16(kf[0][kc], qf[1][kc], r);
                r  = mfma16(kf[1][kc], qf[0][kc], r);
                r  = mfma16(kf[2][kc], qf[2][kc], r);
                r  = mfma16(kf[2][kc], qf[3][kc], r);
                r  = mfma16(kf[3][kc], qf[2][kc], r);
                im = mfma16(kf[0][kc], qf[2][kc], im);
                im = mfma16(kf[0][kc], qf[3][kc], im);
                im = mfma16(kf[1][kc], qf[2][kc], im);
                im = mfma16(kf[2][kc], nqr[0][kc], im);
                im = mfma16(kf[2][kc], nqr[1][kc], im);
                im = mfma16(kf[3][kc], nqr[0][kc], im);
                sr[ni] = r; si[ni] = im;
            }
        }

        // ---- online softmax on |S| ----
        float mag[4][4], srs[4][4], sis[4][4];
        float mx = -1e30f;
#pragma unroll
        for (int ni = 0; ni < 4; ni++)
#pragma unroll
            for (int r = 0; r < 4; r++) {
                float a = sr[ni][r] * SCALE_, b = si[ni][r] * SCALE_;
                srs[ni][r] = a; sis[ni][r] = b;
                float mg = sqrtf(a * a + b * b);
                mag[ni][r] = mg;
                mx = fmaxf(mx, mg);
            }
        mx = fmaxf(mx, __shfl_xor(mx, 16, 64));
        mx = fmaxf(mx, __shfl_xor(mx, 32, 64));
        float newm = fmaxf(mrow, mx);
        float alpha = expf(mrow - newm);
        mrow = newm;
        float psum = 0.f;
#pragma unroll
        for (int ni = 0; ni < 4; ni++)
#pragma unroll
            for (int r = 0; r < 4; r++) {
                float p = expf(mag[ni][r] - newm);
                psum += p;
                float sc = (mag[ni][r] > 0.f) ? (p / mag[ni][r]) : 0.f;
                float pr = (mag[ni][r] > 0.f) ? srs[ni][r] * sc : p;
                float pi = sis[ni][r] * sc;
                int key = ni * 16 + quad * 4 + r;
                prb[m16 * 66 + key] = pr;
                pib[m16 * 66 + key] = pi;
            }
        psum += __shfl_xor(psum, 16, 64);
        psum += __shfl_xor(psum, 32, 64);
        lrow = lrow * alpha + psum;
#pragma unroll
        for (int ni = 0; ni < 4; ni++)
#pragma unroll
            for (int r = 0; r < 4; r++) { Oa[ni][0][r] *= alpha; Oa[ni][1][r] *= alpha; }

        // ---- P fragments via per-wave LDS transpose ----
        short8 prh[2], prl[2], pihf[2], pilf[2], nih[2], nil2[2];
#pragma unroll
        for (int kc = 0; kc < 2; kc++) {
            unsigned short a0[8], a1[8], b0[8], b1[8];
#pragma unroll
            for (int j = 0; j < 8; j++) {
                float vr = prb[m16 * 66 + kc * 32 + quad * 8 + j];
                float vi = pib[m16 * 66 + kc * 32 + quad * 8 + j];
                split2(vr, a0[j], a1[j]);
                split2(vi, b0[j], b1[j]);
            }
            short8 x0, x1, y0, y1;
#pragma unroll
            for (int j = 0; j < 8; j++) {
                x0[j] = (short)a0[j]; x1[j] = (short)a1[j];
                y0[j] = (short)b0[j]; y1[j] = (short)b1[j];
            }
            prh[kc] = x0; prl[kc] = x1; pihf[kc] = y0; pilf[kc] = y1;
            nih[kc] = neg8(y0); nil2[kc] = neg8(y1);
        }

        // ---- O^T += V^T P^T ----
#pragma unroll
        for (int ni = 0; ni < 4; ni++) {
            size_t vbase = (size_t)(bb * INNER_ + hh * DHEAD_ + ni * 16 + m16) * N_ + kt * 64;
            short8 vf[4][2];
#pragma unroll
            for (int p = 0; p < 4; p++)
#pragma unroll
                for (int kc = 0; kc < 2; kc++)
                    vf[p][kc] = *(const short8*)(wtp + (size_t)p * S + vbase + kc * 32 + quad * 8);
#pragma unroll
            for (int kc = 0; kc < 2; kc++) {
                f32x4 orv = Oa[ni][0], oiv = Oa[ni][1];
                orv = mfma16(vf[0][kc], prh[kc], orv);
                orv = mfma16(vf[0][kc], prl[kc], orv);
                orv = mfma16(vf[1][kc], prh[kc], orv);
                orv = mfma16(vf[2][kc], nih[kc], orv);
                orv = mfma16(vf[2][kc], nil2[kc], orv);
                orv = mfma16(vf[3][kc], nih[kc], orv);
                oiv = mfma16(vf[0][kc], pihf[kc], oiv);
                oiv = mfma16(vf[0][kc], pilf[kc], oiv);
                oiv = mfma16(vf[1][kc], pihf[kc], oiv);
                oiv = mfma16(vf[2][kc], prh[kc], oiv);
                oiv = mfma16(vf[2][kc], prl[kc], oiv);
                oiv = mfma16(vf[3][kc], prh[kc], oiv);
                Oa[ni][0] = orv; Oa[ni][1] = oiv;
            }
        }
    }

    // ---- 4-way merge across waves ----
    if (wave != 0) {
        float* mb = &Pb[wave][0];
#pragma unroll
        for (int ni = 0; ni < 4; ni++)
#pragma unroll
            for (int r = 0; r < 4; r++) {
                mb[lane * 33 + ni * 8 + r]     = Oa[ni][0][r];
                mb[lane * 33 + ni * 8 + 4 + r] = Oa[ni][1][r];
            }
        mlbuf[wave][lane][0] = mrow;
        mlbuf[wave][lane][1] = lrow;
    }
    __syncthreads();
    if (wave == 0) {
        float mm = mrow;
#pragma unroll
        for (int w = 1; w < 4; w++) mm = fmaxf(mm, mlbuf[w][lane][0]);
        float a0 = expf(mrow - mm);
        float ltot = a0 * lrow;
        float aw[3];
#pragma unroll
        for (int w = 1; w < 4; w++) {
            aw[w - 1] = expf(mlbuf[w][lane][0] - mm);
            ltot += aw[w - 1] * mlbuf[w][lane][1];
        }
        float invl = 1.f / ltot;
        size_t obase = (size_t)(bb * N_ + q0 + m16) * INNER_ + hh * DHEAD_;
#pragma unroll
        for (int ni = 0; ni < 4; ni++)
#pragma unroll
            for (int r = 0; r < 4; r++) {
                float vr = a0 * Oa[ni][0][r];
                float vi = a0 * Oa[ni][1][r];
#pragma unroll
                for (int w = 1; w < 4; w++) {
                    vr += aw[w - 1] * Pb[w][lane * 33 + ni * 8 + r];
                    vi += aw[w - 1] * Pb[w][lane * 33 + ni * 8 + 4 + r];
                }
                vr *= invl; vi *= invl;
                unsigned short h0, h1, h2, h3;
                split2(vr, h0, h1);
                split2(vi, h2, h3);
                size_t o = obase + ni * 16 + quad * 4 + r;
                aop[0 * (size_t)S + o] = h0;
                aop[1 * (size_t)S + o] = h1;
                aop[2 * (size_t)S + o] = h2;
                aop[3 * (size_t)S + o] = h3;
            }
    }
}

// ---------------- output pack (fallback only) ----------------
__global__ void pack_planar(const float* __restrict__ xr, const float* __restrict__ xi,
                            float* __restrict__ out, int S, int cap) {
    int idx = blockIdx.x * 256 + threadIdx.x;
    if (idx < cap) out[idx] = xr[idx];
    if (S + idx < cap) out[S + idx] = xi[idx];
}

__global__ void pack_real(const float* __restrict__ xr, float* __restrict__ out, int cap) {
    int idx = blockIdx.x * 256 + threadIdx.x;
    if (idx < cap) out[idx] = xr[idx];
}

// ---------------- host orchestration ----------------
extern "C" void kernel_launch(void* const* d_in, const int* in_sizes, int n_in,
                              void* d_out, int out_size, void* d_ws, size_t ws_size,
                              hipStream_t stream) {
    const float* in_xre = (const float*)d_in[0];
    const float* in_xim = (const float*)d_in[1];
    const float* ln1wr = (const float*)d_in[2];
    const float* ln1wi = (const float*)d_in[3];
    const float* ln1br = (const float*)d_in[4];
    const float* ln1bi = (const float*)d_in[5];
    const float* qkvr  = (const float*)d_in[6];
    const float* qkvi  = (const float*)d_in[7];
    const float* outwr = (const float*)d_in[8];
    const float* outwi = (const float*)d_in[9];
    const float* outbr = (const float*)d_in[10];
    const float* outbi = (const float*)d_in[11];
    const float* ln2wr = (const float*)d_in[12];
    const float* ln2wi = (const float*)d_in[13];
    const float* ln2br = (const float*)d_in[14];
    const float* ln2bi = (const float*)d_in[15];
    const float* ffr   = (const float*)d_in[16];
    const float* ffi   = (const float*)d_in[17];

    const size_t S = (size_t)B_ * N_ * DIM_;          // 524288
    const int    Si = (int)S;

    float* ws  = (float*)d_ws;
    float* xre = ws;            float* xim = xre + S;
    float* xnr = xim + S;       float* xni = xnr + S;   // 4*S fp32 = 8 MB

    unsigned short* xnp   = (unsigned short*)(xni + S);
    unsigned short* aop   = xnp + 4 * S;
    unsigned short* wpb   = aop + 4 * S;
    unsigned short* wtpb  = wpb + 4 * S;
    unsigned short* qkvp  = wtpb + 4 * S;
    unsigned short* outwp = qkvp + (size_t)DEPTH_ * 4 * 65536;
    unsigned short* ffp   = outwp + (size_t)DEPTH_ * 4 * 65536;

    wsplit<<<DEPTH_ * 65536 / 256, 256, 0, stream>>>(qkvr, qkvi, qkvp);
    wsplit<<<DEPTH_ * 65536 / 256, 256, 0, stream>>>(outwr, outwi, outwp);
    wsplit<<<DEPTH_ * 65536 / 256, 256, 0, stream>>>(ffr, ffi, ffp);

    const int MR = B_ * N_;
    dim3 gGemm(MR / 16, INNER_ / 16);    // (128, 16): x = M-tile -> XCD-local A
    dim3 gAttn(B_ * HEADS_, N_ / 16);    // (8, 64): x = (b,h) -> XCD-local K/V
    int eBlocks = (int)(S / 256);

    bool directOut = (out_size >= (int)(2 * S));
    float* foutR = directOut ? (float*)d_out : xre;
    float* foutI = directOut ? (float*)d_out + S : xim;

    for (int l = 0; l < DEPTH_; l++) {
        const float* xinR = (l == 0) ? in_xre : xre;
        const float* xinI = (l == 0) ? in_xim : xim;

        ln_kernel<<<MR, DIM_, 0, stream>>>(xinR, xinI,
            ln1wr + l * DIM_, ln1wi + l * DIM_, ln1br + l * DIM_, ln1bi + l * DIM_,
            xnr, xni, xnp, Si);

        gemm_mfma<1><<<gGemm, 64, 0, stream>>>(xnp, Si, qkvp + (size_t)l * 4 * 65536,
            wpb, wtpb, nullptr, nullptr, nullptr, nullptr, nullptr, nullptr, Si);

        attn_mfma<<<gAttn, 256, 0, stream>>>(wpb, wtpb, aop, Si);

        gemm_mfma<2><<<gGemm, 64, 0, stream>>>(aop, Si, outwp + (size_t)l * 4 * 65536,
            nullptr, nullptr, outbr + l * DIM_, outbi + l * DIM_, xinR, xinI, xre, xim, Si);

        ln_kernel<<<MR, DIM_, 0, stream>>>(xre, xim,
            ln2wr + l * DIM_, ln2wi + l * DIM_, ln2br + l * DIM_, ln2bi + l * DIM_,
            xnr, xni, xnp, Si);

        // FF + CReLU; last layer writes planar output directly to d_out
        float* oR = (l == DEPTH_ - 1) ? foutR : xre;
        float* oI = (l == DEPTH_ - 1) ? foutI : xim;
        gemm_mfma<3><<<gGemm, 64, 0, stream>>>(xnp, Si, ffp + (size_t)l * 4 * 65536,
            nullptr, nullptr, nullptr, nullptr, xnr, xni, oR, oI, Si);
    }

    if (!directOut) {
        pack_real<<<eBlocks, 256, 0, stream>>>(xre, (float*)d_out, out_size);
    }
}